// Round 10
// baseline (838.475 us; speedup 1.0000x reference)
//
#include <hip/hip_runtime.h>
#include <hip/hip_bf16.h>
#include <cstdint>
#include <cstddef>

#define Bb 16
#define Kk 2048
#define Pp 512
#define Ss 16
#define Cc 256

typedef __attribute__((ext_vector_type(8))) short bf16x8;
typedef __attribute__((ext_vector_type(4))) float f32x4;
typedef float v2f __attribute__((ext_vector_type(2)));

__device__ __forceinline__ unsigned short f2bf(float x) {  // RNE
  unsigned u = __float_as_uint(x);
  u = (u + 0x7FFF + ((u >> 16) & 1)) >> 16;
  return (unsigned short)u;
}
__device__ __forceinline__ float bf2f(unsigned short s) {
  return __uint_as_float((unsigned)s << 16);
}
// truncation split: x ~= hi + lo with |x-hi-lo| <= 2^-16 |x|
__device__ __forceinline__ void split2(float x, short& h, short& l) {
  unsigned u = __float_as_uint(x);
  h = (short)(u >> 16);
  float r = x - __uint_as_float(u & 0xFFFF0000u);
  l = (short)(__float_as_uint(r) >> 16);
}

// ---------------- workspace layout (bytes) ----------------
static constexpr size_t OFF_TNORM = 0;                          // 20480
static constexpr size_t OFF_SUMS  = 20480;                      // 16384
static constexpr size_t OFF_INDS  = 36864;                      // 32768
static constexpr size_t OFF_IDXL  = 69632;                      // 524288
static constexpr size_t OFF_GX    = 593920;                     // 1572864
static constexpr size_t OFF_F1    = 2166784;                    // 16777216 f32
static constexpr size_t OFF_BIGA  = 18944000;                   // 67108864
static constexpr size_t OFF_BIGB  = 86052864;                   // 67108864
static constexpr size_t OFF_NET   = 153161728;                  // 2260992 f32 (8192x69)
static constexpr size_t OFF_WTH   = 155422720;                  // 1540096 bf16
static constexpr size_t OFF_WTL   = 156962816;                  // 1540096 bf16
// BIGA: L2OUT bf16 (0..33.5M, dead after L3); QF f32 (0..16.7M, from h2 on)
// BIGB: FEAT +0 (4M) | C1F +4M | C2F +8M | CLIPF +12M (8M) | H0F +20M (16M)
//       | H1F +36M (16M)

// Wt element offsets ([N][K] row-major bf16)
#define WT_GW1 0
#define WT_GW2 16384
#define WT_C1  32768
#define WT_C2  49152
#define WT_H0  65536
#define WT_H1  196608
#define WT_H2  458752
#define WT_C3  720896   // 384x128 (N padded, rows >=325 zero)

// sum-slot float offsets inside OFF_SUMS
#define SB0S 0
#define SB0Q 128
#define SB1S 256
#define SB1Q 384
#define SB2S 512
#define SB2Q 640
#define SC1S 768
#define SC1Q 896
#define SC2S 1024
#define SC2Q 1152
#define SH0S 1280
#define SH0Q 1792
#define SH1S 2304
#define SH1Q 2816

template <int CTRL>
__device__ __forceinline__ float fmax_dpp(float v) {
  int o = __builtin_amdgcn_update_dpp(0, __float_as_int(v), CTRL, 0xF, 0xF, true);
  return fmaxf(v, __int_as_float(o));
}

// fused: fps (0..15) | F1 gemm (16..527) | tnorm (528) | wprep (529..628)
__global__ __launch_bounds__(256, 1) void fused_pre(
    const float* __restrict__ xyz, int* __restrict__ inds,
    const float* __restrict__ features, const float* __restrict__ g_w0,
    float* __restrict__ F1, const float* __restrict__ text,
    float* __restrict__ tn, const float* __restrict__ g_w1,
    const float* __restrict__ g_w2, const float* __restrict__ conv1_w,
    const float* __restrict__ conv2_w, const float* __restrict__ conv3_w,
    const float* __restrict__ h_w0, const float* __restrict__ h_w1,
    const float* __restrict__ h_w2, unsigned short* __restrict__ wth,
    unsigned short* __restrict__ wtl) {
  __shared__ __align__(16) float smem[8208];
  const int tid = threadIdx.x;

  if (blockIdx.x < 16) {
    // ===== FPS: 4 waves, thread-major k = tid*8+j ==========================
    // Mailbox carries winner {key, x,y,z}: one LDS latency round per iter.
    #pragma clang fp contract(off)
    const int b = blockIdx.x;
    unsigned long long (*redk)[4] = (unsigned long long(*)[4])smem;  // 16 f
    float4 (*redc)[4] = (float4(*)[4])(smem + 16);                   // 32 f
    const float* base = xyz + (size_t)b * Kk * 3;
    if (tid == 0) inds[b * Pp] = 0;
    v2f PX[4], PY[4], PZ[4], DM[4];
    {
      const float* pb = base + tid * 24;
      float4 f0 = *(const float4*)(pb + 0);
      float4 f1 = *(const float4*)(pb + 4);
      float4 f2 = *(const float4*)(pb + 8);
      float4 f3 = *(const float4*)(pb + 12);
      float4 f4 = *(const float4*)(pb + 16);
      float4 f5 = *(const float4*)(pb + 20);
      PX[0] = (v2f){f0.x, f0.w}; PY[0] = (v2f){f0.y, f1.x}; PZ[0] = (v2f){f0.z, f1.y};
      PX[1] = (v2f){f1.z, f2.y}; PY[1] = (v2f){f1.w, f2.z}; PZ[1] = (v2f){f2.x, f2.w};
      PX[2] = (v2f){f3.x, f3.w}; PY[2] = (v2f){f3.y, f4.x}; PZ[2] = (v2f){f3.z, f4.y};
      PX[3] = (v2f){f4.z, f5.y}; PY[3] = (v2f){f4.w, f5.z}; PZ[3] = (v2f){f5.x, f5.w};
      #pragma unroll
      for (int p = 0; p < 4; p++) DM[p] = (v2f){1e10f, 1e10f};
    }
    // seed: point 0 (inds[0] = 0)
    float lx = base[0], ly = base[1], lz = base[2];
    const int lane = tid & 63, wid = tid >> 6;
    for (int it = 1; it < Pp; ++it) {
      v2f vlx = {lx, lx}, vly = {ly, ly}, vlz = {lz, lz};
      float pf[4];
      int pk_[4];
      #pragma unroll
      for (int p = 0; p < 4; p++) {
        v2f dx = PX[p] - vlx, dy = PY[p] - vly, dz = PZ[p] - vlz;
        v2f d = (dx * dx + dy * dy) + dz * dz;  // contract off: exact mul/add
        v2f m2 = __builtin_elementwise_min(DM[p], d);
        DM[p] = m2;
        bool t = m2.y > m2.x;
        pf[p] = t ? m2.y : m2.x;
        pk_[p] = 2 * p + (t ? 1 : 0);
      }
      bool t01 = pf[1] > pf[0];
      float f01 = t01 ? pf[1] : pf[0];
      int k01 = t01 ? pk_[1] : pk_[0];
      bool t23 = pf[3] > pf[2];
      float f23 = t23 ? pf[3] : pf[2];
      int k23 = t23 ? pk_[3] : pk_[2];
      bool tt = f23 > f01;
      float bf = tt ? f23 : f01;
      int bj = tt ? k23 : k01;
      float g = bf;
      g = fmax_dpp<0xB1>(g);   // xor 1
      g = fmax_dpp<0x4E>(g);   // xor 2
      g = fmax_dpp<0x141>(g);  // xor 7
      g = fmax_dpp<0x140>(g);  // xor 15
      g = fmax_dpp<0x142>(g);  // row_bcast15
      g = fmax_dpp<0x143>(g);  // row_bcast31 -> lane63 = wave max
      float gs = __uint_as_float(
          (unsigned)__builtin_amdgcn_readlane(__float_as_int(g), 63));
      unsigned long long msk = __ballot(bf == gs);
      int src = __builtin_ctzll(msk);  // lowest lane = lowest k (thread-major)
      if (lane == src) {
        int p = bj >> 1;
        float wx = (bj & 1) ? PX[p].y : PX[p].x;
        float wy = (bj & 1) ? PY[p].y : PY[p].x;
        float wz = (bj & 1) ? PZ[p].y : PZ[p].x;
        int kk = (tid << 3) | bj;
        redk[it & 1][wid] = ((unsigned long long)__float_as_uint(gs) << 32) |
                            (unsigned)(~(unsigned)kk);
        redc[it & 1][wid] = make_float4(wx, wy, wz, 0.f);
      }
      __syncthreads();
      unsigned long long q0 = redk[it & 1][0], q1 = redk[it & 1][1];
      unsigned long long q2 = redk[it & 1][2], q3 = redk[it & 1][3];
      float4 c0 = redc[it & 1][0], c1 = redc[it & 1][1];
      float4 c2 = redc[it & 1][2], c3 = redc[it & 1][3];
      bool s01 = q0 > q1;
      unsigned long long m01 = s01 ? q0 : q1;
      float4 cc01 = s01 ? c0 : c1;
      bool s23 = q2 > q3;
      unsigned long long m23 = s23 ? q2 : q3;
      float4 cc23 = s23 ? c2 : c3;
      bool sw = m23 > m01;
      unsigned long long mm = sw ? m23 : m01;
      float4 cw = sw ? cc23 : cc01;
      lx = cw.x; ly = cw.y; lz = cw.z;
      if (tid == 0) inds[b * Pp + it] = (int)(~(unsigned)mm);
    }
  } else if (blockIdx.x == 528) {
    int w = tid >> 6, lane = tid & 63;
    for (int r = w; r < 10; r += 4) {
      const float* rw = text + (size_t)r * 512;
      float v[8];
      float ss = 0.f;
      #pragma unroll
      for (int u = 0; u < 8; u++) { v[u] = rw[lane + 64 * u]; ss += v[u] * v[u]; }
      #pragma unroll
      for (int off = 32; off; off >>= 1) ss += __shfl_xor(ss, off, 64);
      float nrm = sqrtf(ss);
      #pragma unroll
      for (int u = 0; u < 8; u++)
        tn[(size_t)r * 512 + lane + 64 * u] = v[u] / nrm;
    }
  } else if (blockIdx.x >= 529) {
    // ===== weight transpose + RNE bf16 split (parallel, 100 blocks) =======
    int wb = blockIdx.x - 529;
    const float* W;
    int K, N, NS, nblk, pidx;
    unsigned short *dh, *dl;
    if (wb < 4)       { W = g_w1;    K = 128; N = 128; NS = 128; dh = wth + WT_GW1; dl = wtl + WT_GW1; nblk = 4;  pidx = wb; }
    else if (wb < 8)  { W = g_w2;    K = 128; N = 128; NS = 128; dh = wth + WT_GW2; dl = wtl + WT_GW2; nblk = 4;  pidx = wb - 4; }
    else if (wb < 12) { W = conv1_w; K = 128; N = 128; NS = 128; dh = wth + WT_C1;  dl = wtl + WT_C1;  nblk = 4;  pidx = wb - 8; }
    else if (wb < 16) { W = conv2_w; K = 128; N = 128; NS = 128; dh = wth + WT_C2;  dl = wtl + WT_C2;  nblk = 4;  pidx = wb - 12; }
    else if (wb < 32) { W = h_w0;    K = 256; N = 512; NS = 512; dh = wth + WT_H0;  dl = wtl + WT_H0;  nblk = 16; pidx = wb - 16; }
    else if (wb < 64) { W = h_w1;    K = 512; N = 512; NS = 512; dh = wth + WT_H1;  dl = wtl + WT_H1;  nblk = 32; pidx = wb - 32; }
    else if (wb < 96) { W = h_w2;    K = 512; N = 512; NS = 512; dh = wth + WT_H2;  dl = wtl + WT_H2;  nblk = 32; pidx = wb - 64; }
    else              { W = conv3_w; K = 128; N = 384; NS = 325; dh = wth + WT_C3;  dl = wtl + WT_C3;  nblk = 4;  pidx = wb - 96; }
    for (int idx = pidx * 256 + tid; idx < K * N; idx += nblk * 256) {
      int k = idx / N, n = idx - k * N;
      float w = (n < NS) ? W[k * NS + n] : 0.f;
      unsigned short hi = f2bf(w);
      unsigned short lo = f2bf(w - bf2f(hi));
      dh[n * K + k] = hi;
      dl[n * K + k] = lo;
    }
  } else {
    // ===== F1 = feats_kc @ g_w0[3:,:]  (32768 x 256 x 128) ================
    float (*a_t)[68] = (float(*)[68])smem;
    float (*b_t)[128] = (float(*)[128])(smem + 32 * 68);
    const float* W = g_w0 + 3 * 128;
    const int m0 = (blockIdx.x - 16) * 64;
    float acc[4][8];
    #pragma unroll
    for (int i = 0; i < 4; i++)
      #pragma unroll
      for (int j = 0; j < 8; j++) acc[i][j] = 0.f;
    const int ty = tid >> 4, tx = tid & 15;
    const int lr = tid & 63, wv = tid >> 6;
    const int bb = m0 >> 11, k0 = m0 & 2047;
    const float* fb = features + (size_t)bb * (Cc * Kk);
    for (int c0 = 0; c0 < 256; c0 += 32) {
      #pragma unroll
      for (int i = 0; i < 8; i++) {
        int c = c0 + wv + 4 * i;
        a_t[wv + 4 * i][lr] = fb[(size_t)c * Kk + k0 + lr];
      }
      #pragma unroll
      for (int p = 0; p < 4; p++) {
        int cc = p * 8 + (tid >> 5);
        int nl = (tid & 31) * 4;
        *(float4*)&b_t[cc][nl] = *(const float4*)&W[(size_t)(c0 + cc) * 128 + nl];
      }
      __syncthreads();
      #pragma unroll
      for (int kk = 0; kk < 32; kk++) {
        float4 av = *(const float4*)&a_t[kk][ty * 4];
        float4 b0 = *(const float4*)&b_t[kk][tx * 4];
        float4 b1 = *(const float4*)&b_t[kk][tx * 4 + 64];
        float ap[4] = {av.x, av.y, av.z, av.w};
        float bq0[4] = {b0.x, b0.y, b0.z, b0.w};
        float bq1[4] = {b1.x, b1.y, b1.z, b1.w};
        #pragma unroll
        for (int i = 0; i < 4; i++) {
          #pragma unroll
          for (int u = 0; u < 4; u++) {
            acc[i][u] = fmaf(ap[i], bq0[u], acc[i][u]);
            acc[i][4 + u] = fmaf(ap[i], bq1[u], acc[i][4 + u]);
          }
        }
      }
      __syncthreads();
    }
    #pragma unroll
    for (int i = 0; i < 4; i++) {
      size_t mrow = (size_t)(m0 + ty * 4 + i);
      #pragma unroll
      for (int gq = 0; gq < 2; gq++) {
        float4 v4 = make_float4(acc[i][gq * 4], acc[i][gq * 4 + 1],
                                acc[i][gq * 4 + 2], acc[i][gq * 4 + 3]);
        *(float4*)&F1[mrow * 128 + gq * 64 + tx * 4] = v4;
      }
    }
  }
}

// -------- neighbor selection + bn0 stats (xyz staged in LDS) --------
__global__ __launch_bounds__(256) void neigh_k(
    const float* __restrict__ xyz, const int* __restrict__ inds,
    const float* __restrict__ F1, const float* __restrict__ g_w0,
    int* __restrict__ idxl, float* __restrict__ gx, float* __restrict__ s0,
    float* __restrict__ q0) {
  __shared__ float rs[128], rq[128];
  __shared__ __align__(16) float4 pts[Kk];  // 32KB, all 4 waves same batch
  const int tid = threadIdx.x;
  if (tid < 128) { rs[tid] = 0.f; rq[tid] = 0.f; }
  int widx = blockIdx.x * 4 + (tid >> 6);
  int lane = tid & 63;
  int b = widx >> 9;
  const float* base = xyz + (size_t)b * Kk * 3;
  for (int i = tid; i < Kk; i += 256)
    pts[i] = make_float4(base[3 * i], base[3 * i + 1], base[3 * i + 2], 0.f);
  __syncthreads();
  int q = inds[widx];
  float4 Q = pts[q];
  float qx = Q.x, qy = Q.y, qz = Q.z;
  int cnt = 0;
  int myk = 0;
  for (int ch = 0; ch < 32 && cnt < Ss; ch++) {
    float4 P = pts[ch * 64 + lane];
    float dx = P.x - qx;
    float dy = P.y - qy;
    float dz = P.z - qz;
    float d2 = __fadd_rn(__fadd_rn(__fmul_rn(dx, dx), __fmul_rn(dy, dy)),
                         __fmul_rn(dz, dz));
    unsigned long long m = __ballot(d2 < 0.09f);
    while (m && cnt < Ss) {
      int t = __builtin_ctzll(m);
      if (lane == cnt) myk = ch * 64 + t;
      cnt++;
      m &= m - 1;
    }
  }
  int first = __shfl(myk, 0, 64);
  int kksel = 0;
  float g0r = 0.f, g1r = 0.f, g2r = 0.f;
  if (lane < Ss) {
    int kk = (lane < cnt) ? myk : first;
    kksel = kk;
    float4 P = pts[kk];
    g0r = (P.x - qx) / 0.3f;
    g1r = (P.y - qy) / 0.3f;
    g2r = (P.z - qz) / 0.3f;
    size_t o = (size_t)widx * Ss + lane;
    idxl[o] = kk;
    gx[o * 3 + 0] = g0r;
    gx[o * 3 + 1] = g1r;
    gx[o * 3 + 2] = g2r;
  }
  // ---- bn0 stats over the 16 gathered rows (cols: lane and lane+64) ----
  const float* f1b = F1 + (size_t)(b << 11) * 128;
  float wa0 = g_w0[lane], wa1 = g_w0[128 + lane], wa2 = g_w0[256 + lane];
  float wb0 = g_w0[64 + lane], wb1 = g_w0[192 + lane], wb2 = g_w0[320 + lane];
  float sa = 0.f, qa = 0.f, sb = 0.f, qb = 0.f;
  #pragma unroll
  for (int s = 0; s < Ss; s++) {
    int bidx = __shfl(kksel, s, 64);
    float gg0 = __shfl(g0r, s, 64);
    float gg1 = __shfl(g1r, s, 64);
    float gg2 = __shfl(g2r, s, 64);
    const float* fr = f1b + (size_t)bidx * 128;
    float va = fr[lane] + gg0 * wa0 + gg1 * wa1 + gg2 * wa2;
    float vb = fr[64 + lane] + gg0 * wb0 + gg1 * wb1 + gg2 * wb2;
    sa += va; qa += va * va;
    sb += vb; qb += vb * vb;
  }
  atomicAdd(&rs[lane], sa);
  atomicAdd(&rq[lane], qa);
  atomicAdd(&rs[64 + lane], sb);
  atomicAdd(&rq[64 + lane], qb);
  __syncthreads();
  if (tid < 128) {
    atomicAdd(&s0[tid], rs[tid]);
    atomicAdd(&q0[tid], rq[tid]);
  }
}

// ------- split-bf16 MFMA GEMM: out = act_in(A) @ (Wh+Wl)^T (+bias) ---------
// GATHER: A[row] = F1[gidx[row]] + gx(row).w_xyz  (inline gather, f32 src)
// ABF16 : A stored bf16. OBF16: store bf16.
// OMAX  : emit per-16-row-group max. WCLIP: split cols -> net / clipf.
template <int KD, bool INBN, bool HASBIAS, bool OSUM, bool OMAX, bool WCLIP,
          bool ABF16, bool GATHER, bool OBF16>
__global__ __launch_bounds__(256, 2) void gemm_mfma(
    const void* __restrict__ A, const unsigned short* __restrict__ Wh,
    const unsigned short* __restrict__ Wl, const float* __restrict__ bias,
    const float* __restrict__ isum, const float* __restrict__ isq,
    float inv_cnt, const float* __restrict__ gamma,
    const float* __restrict__ beta, void* __restrict__ outp, int N, int nout,
    float* __restrict__ clipf, float* __restrict__ osum,
    float* __restrict__ osq, const int* __restrict__ idxl,
    const float* __restrict__ gxv, const float* __restrict__ w0raw) {
  __shared__ float sc[INBN ? KD : 1];
  __shared__ float sh[INBN ? KD : 1];
  __shared__ float red_s[OSUM ? 128 : 1];
  __shared__ float red_q[OSUM ? 128 : 1];
  const int tid = threadIdx.x;
  if (INBN) {
    for (int c = tid; c < KD; c += 256) {
      float mean = isum[c] * inv_cnt;
      float var = isq[c] * inv_cnt - mean * mean;
      float is_ = rsqrtf(var + 1e-5f);
      float scl = gamma[c] * is_;
      sc[c] = scl;
      sh[c] = beta[c] - mean * scl;
    }
  }
  if (OSUM && tid < 128) { red_s[tid] = 0.f; red_q[tid] = 0.f; }
  __syncthreads();
  const int wave = tid >> 6, lane = tid & 63;
  const int wm = wave >> 1, wn = wave & 1;
  const int r = lane & 15, g = lane >> 4;
  const size_t m0 = (size_t)blockIdx.x * 128 + wm * 64;
  const int n0 = blockIdx.y * 128 + wn * 64;

  const float* Af = (const float*)A;
  const unsigned short* Ab = (const unsigned short*)A;

  size_t gi[4];
  float gx0[4], gx1[4], gx2[4];
  if (GATHER) {
    #pragma unroll
    for (int mf = 0; mf < 4; mf++) {
      int row = (int)m0 + mf * 16 + r;
      gi[mf] = ((size_t)((row >> 13) << 11) + idxl[row]) * 128;
      gx0[mf] = gxv[3 * (size_t)row];
      gx1[mf] = gxv[3 * (size_t)row + 1];
      gx2[mf] = gxv[3 * (size_t)row + 2];
    }
  }

  f32x4 acc[4][4] = {};
  for (int ks = 0; ks < KD / 32; ks++) {
    const int kb = ks * 32 + g * 8;
    bf16x8 bh[4], bl[4];
    #pragma unroll
    for (int nf = 0; nf < 4; nf++) {
      bh[nf] = *(const bf16x8*)&Wh[(size_t)(n0 + nf * 16 + r) * KD + kb];
      bl[nf] = *(const bf16x8*)&Wl[(size_t)(n0 + nf * 16 + r) * KD + kb];
    }
    float s8[8], h8[8];
    if (INBN) {
      #pragma unroll
      for (int j = 0; j < 8; j++) { s8[j] = sc[kb + j]; h8[j] = sh[kb + j]; }
    }
    float wxr[8], wyr[8], wzr[8];
    if (GATHER) {
      float4 a0 = *(const float4*)&w0raw[kb];
      float4 a1 = *(const float4*)&w0raw[kb + 4];
      float4 b0 = *(const float4*)&w0raw[128 + kb];
      float4 b1 = *(const float4*)&w0raw[128 + kb + 4];
      float4 c0 = *(const float4*)&w0raw[256 + kb];
      float4 c1 = *(const float4*)&w0raw[256 + kb + 4];
      wxr[0]=a0.x; wxr[1]=a0.y; wxr[2]=a0.z; wxr[3]=a0.w;
      wxr[4]=a1.x; wxr[5]=a1.y; wxr[6]=a1.z; wxr[7]=a1.w;
      wyr[0]=b0.x; wyr[1]=b0.y; wyr[2]=b0.z; wyr[3]=b0.w;
      wyr[4]=b1.x; wyr[5]=b1.y; wyr[6]=b1.z; wyr[7]=b1.w;
      wzr[0]=c0.x; wzr[1]=c0.y; wzr[2]=c0.z; wzr[3]=c0.w;
      wzr[4]=c1.x; wzr[5]=c1.y; wzr[6]=c1.z; wzr[7]=c1.w;
    }
    #pragma unroll
    for (int mf = 0; mf < 4; mf++) {
      float xv[8];
      if (GATHER) {
        const float* fp = Af + gi[mf] + kb;
        float4 x0 = *(const float4*)fp;
        float4 x1 = *(const float4*)(fp + 4);
        xv[0]=x0.x; xv[1]=x0.y; xv[2]=x0.z; xv[3]=x0.w;
        xv[4]=x1.x; xv[5]=x1.y; xv[6]=x1.z; xv[7]=x1.w;
        #pragma unroll
        for (int j = 0; j < 8; j++)
          xv[j] += gx0[mf] * wxr[j] + gx1[mf] * wyr[j] + gx2[mf] * wzr[j];
      } else if (ABF16) {
        bf16x8 rawv = *(const bf16x8*)&Ab[(m0 + mf * 16 + r) * KD + kb];
        #pragma unroll
        for (int j = 0; j < 8; j++) xv[j] = bf2f((unsigned short)rawv[j]);
      } else {
        const float* ap = Af + (m0 + mf * 16 + r) * KD + kb;
        float4 x0 = *(const float4*)ap;
        float4 x1 = *(const float4*)(ap + 4);
        xv[0]=x0.x; xv[1]=x0.y; xv[2]=x0.z; xv[3]=x0.w;
        xv[4]=x1.x; xv[5]=x1.y; xv[6]=x1.z; xv[7]=x1.w;
      }
      bf16x8 ah, al;
      #pragma unroll
      for (int j = 0; j < 8; j++) {
        float x = xv[j];
        if (INBN) x = fmaxf(fmaf(x, s8[j], h8[j]), 0.f);
        short hh, ll;
        split2(x, hh, ll);
        ah[j] = hh;
        al[j] = ll;
      }
      #pragma unroll
      for (int nf = 0; nf < 4; nf++) {
        acc[mf][nf] = __builtin_amdgcn_mfma_f32_16x16x32_bf16(
            ah, bh[nf], acc[mf][nf], 0, 0, 0);
        acc[mf][nf] = __builtin_amdgcn_mfma_f32_16x16x32_bf16(
            al, bh[nf], acc[mf][nf], 0, 0, 0);
        acc[mf][nf] = __builtin_amdgcn_mfma_f32_16x16x32_bf16(
            ah, bl[nf], acc[mf][nf], 0, 0, 0);
      }
    }
  }
  float bv[4];
  if (HASBIAS) {
    #pragma unroll
    for (int nf = 0; nf < 4; nf++) {
      int col = n0 + nf * 16 + r;
      bv[nf] = (!WCLIP || col < nout) ? bias[col] : 0.f;
    }
  }
  float ps[4] = {0.f, 0.f, 0.f, 0.f}, pq[4] = {0.f, 0.f, 0.f, 0.f};
  #pragma unroll
  for (int mf = 0; mf < 4; mf++) {
    float mx[4];
    #pragma unroll
    for (int nf = 0; nf < 4; nf++) {
      float vmax = -1e30f;
      #pragma unroll
      for (int j = 0; j < 4; j++) {
        float v = acc[mf][nf][j];
        if (HASBIAS) v += bv[nf];
        size_t row = m0 + mf * 16 + g * 4 + j;
        int col = n0 + nf * 16 + r;
        if (OSUM) { ps[nf] += v; pq[nf] += v * v; }
        if (OMAX) {
          vmax = fmaxf(vmax, v);
        } else if (WCLIP) {
          if (col < 69) ((float*)outp)[row * 69 + col] = v;
          else if (col < nout) clipf[row * 256 + (col - 69)] = v;
        } else if (OBF16) {
          ((unsigned short*)outp)[row * N + col] = f2bf(v);
        } else {
          ((float*)outp)[row * N + col] = v;
        }
      }
      mx[nf] = vmax;
    }
    if (OMAX) {
      #pragma unroll
      for (int nf = 0; nf < 4; nf++) {
        float m = mx[nf];
        m = fmaxf(m, __shfl_xor(m, 16, 64));
        m = fmaxf(m, __shfl_xor(m, 32, 64));
        if (g == 0) {
          size_t bq = (m0 >> 4) + mf;
          ((float*)outp)[bq * 128 + n0 + nf * 16 + r] = m;
        }
      }
    }
  }
  if (OSUM) {
    #pragma unroll
    for (int nf = 0; nf < 4; nf++) {
      #pragma unroll
      for (int off = 16; off < 64; off <<= 1) {
        ps[nf] += __shfl_xor(ps[nf], off, 64);
        pq[nf] += __shfl_xor(pq[nf], off, 64);
      }
    }
    if (lane < 16) {
      #pragma unroll
      for (int nf = 0; nf < 4; nf++) {
        int lcol = wn * 64 + nf * 16 + r;
        atomicAdd(&red_s[lcol], ps[nf]);
        atomicAdd(&red_q[lcol], pq[nf]);
      }
    }
    __syncthreads();
    if (tid < 128) {
      atomicAdd(&osum[blockIdx.y * 128 + tid], red_s[tid]);
      atomicAdd(&osq[blockIdx.y * 128 + tid], red_q[tid]);
    }
  }
}

// ---------------- final: q-norm, logits, coalesced transpose-assemble -------
__global__ __launch_bounds__(512) void final2(const float* __restrict__ net,
                                              const float* __restrict__ qbuf,
                                              const float* __restrict__ tn,
                                              float* __restrict__ out) {
  __shared__ float tile[79][65];
  const int blk = blockIdx.x;
  const int tid = threadIdx.x;
  const int r = tid >> 3, oct = tid & 7;
  const int row = blk * 64 + r;
  const int b = (blk * 64) >> 9, p0 = (blk * 64) & 511;

  const float* qr = qbuf + (size_t)row * 512 + oct * 64;
  float4 q4[16];
  #pragma unroll
  for (int i = 0; i < 16; i++) q4[i] = *(const float4*)(qr + 4 * i);
  float ss = 0.f;
  float dot[10];
  #pragma unroll
  for (int t = 0; t < 10; t++) dot[t] = 0.f;
  #pragma unroll
  for (int i = 0; i < 16; i++) {
    float4 a = q4[i];
    ss += a.x * a.x + a.y * a.y + a.z * a.z + a.w * a.w;
    #pragma unroll
    for (int t = 0; t < 10; t++) {
      float4 b4 = *(const float4*)(tn + (size_t)t * 512 + oct * 64 + i * 4);
      dot[t] += a.x * b4.x + a.y * b4.y + a.z * b4.z + a.w * b4.w;
    }
  }
  #pragma unroll
  for (int off = 1; off < 8; off <<= 1) {
    ss += __shfl_xor(ss, off, 8);
    #pragma unroll
    for (int t = 0; t < 10; t++) dot[t] += __shfl_xor(dot[t], off, 8);
  }
  if (oct == 0) {
    float inv = rsqrtf(ss) * (1.f / 0.07f);
    #pragma unroll
    for (int t = 0; t < 10; t++) tile[69 + t][r] = dot[t] * inv;
  }
  for (int idx = tid; idx < 64 * 69; idx += 512) {
    int r2 = idx / 69, ch = idx - 69 * r2;
    tile[ch][r2] = net[(size_t)(blk * 64 + r2) * 69 + ch];
  }
  __syncthreads();
  for (int idx = tid; idx < 79 * 64; idx += 512) {
    int ch = idx >> 6, rr = idx & 63;
    out[((size_t)b * 79 + ch) * 512 + p0 + rr] = tile[ch][rr];
  }
}

extern "C" void kernel_launch(void* const* d_in, const int* in_sizes, int n_in,
                              void* d_out, int out_size, void* d_ws,
                              size_t ws_size, hipStream_t stream) {
  const float* xyz = (const float*)d_in[0];
  const float* features = (const float*)d_in[1];
  const float* text = (const float*)d_in[2];
  const float* g_w0 = (const float*)d_in[3];
  const float* g_w1 = (const float*)d_in[4];
  const float* g_w2 = (const float*)d_in[5];
  const float* g_gam0 = (const float*)d_in[6];
  const float* g_bet0 = (const float*)d_in[7];
  const float* g_gam1 = (const float*)d_in[8];
  const float* g_bet1 = (const float*)d_in[9];
  const float* g_gam2 = (const float*)d_in[10];
  const float* g_bet2 = (const float*)d_in[11];
  const float* conv1_w = (const float*)d_in[12];
  const float* conv1_b = (const float*)d_in[13];
  const float* bn1_g = (const float*)d_in[14];
  const float* bn1_b = (const float*)d_in[15];
  const float* conv2_w = (const float*)d_in[16];
  const float* conv2_b = (const float*)d_in[17];
  const float* bn2_g = (const float*)d_in[18];
  const float* bn2_b = (const float*)d_in[19];
  const float* conv3_w = (const float*)d_in[20];
  const float* conv3_b = (const float*)d_in[21];
  const float* h_w0 = (const float*)d_in[22];
  const float* h_b0 = (const float*)d_in[23];
  const float* h_g0 = (const float*)d_in[24];
  const float* h_be0 = (const float*)d_in[25];
  const float* h_w1 = (const float*)d_in[26];
  const float* h_b1 = (const float*)d_in[27];
  const float* h_g1 = (const float*)d_in[28];
  const float* h_be1 = (const float*)d_in[29];
  const float* h_w2 = (const float*)d_in[30];
  const float* h_b2 = (const float*)d_in[31];
  float* out = (float*)d_out;
  char* ws = (char*)d_ws;

  float* tn = (float*)(ws + OFF_TNORM);
  float* sums = (float*)(ws + OFF_SUMS);
  int* inds = (int*)(ws + OFF_INDS);
  int* idxl = (int*)(ws + OFF_IDXL);
  float* gx = (float*)(ws + OFF_GX);
  float* F1 = (float*)(ws + OFF_F1);
  unsigned short* L2OUT = (unsigned short*)(ws + OFF_BIGA);
  float* QF = (float*)(ws + OFF_BIGA);
  float* FEAT = (float*)(ws + OFF_BIGB);
  float* C1F = (float*)(ws + OFF_BIGB + 4194304);
  float* C2F = (float*)(ws + OFF_BIGB + 8388608);
  float* CLIPF = (float*)(ws + OFF_BIGB + 12582912);
  float* H0F = (float*)(ws + OFF_BIGB + 20971520);
  float* H1F = (float*)(ws + OFF_BIGB + 37748736);
  float* net = (float*)(ws + OFF_NET);
  unsigned short* WTH = (unsigned short*)(ws + OFF_WTH);
  unsigned short* WTL = (unsigned short*)(ws + OFF_WTL);

  hipMemsetAsync(sums, 0, 16384, stream);
  fused_pre<<<629, 256, 0, stream>>>(xyz, inds, features, g_w0, F1, text, tn,
                                     g_w1, g_w2, conv1_w, conv2_w, conv3_w,
                                     h_w0, h_w1, h_w2, WTH, WTL);
  // neighbor selection + bn0 stats
  neigh_k<<<2048, 256, 0, stream>>>(xyz, inds, F1, g_w0, idxl, gx,
                                    sums + SB0S, sums + SB0Q);
  // L2 = relu(bn0(gather(F1)+gx.w)) @ g_w1  (inline gather, bf16 out)
  gemm_mfma<128, true, false, true, false, false, false, true, true>
      <<<dim3(1024, 1), 256, 0, stream>>>(
          F1, WTH + WT_GW1, WTL + WT_GW1, nullptr, sums + SB0S, sums + SB0Q,
          1.f / 131072.f, g_gam0, g_bet0, L2OUT, 128, 128, nullptr,
          sums + SB1S, sums + SB1Q, idxl, gx, g_w0);
  // L3 = relu(bn1(L2)) @ g_w2, fused raw max over S=16 -> FEAT (+bn2 stats)
  gemm_mfma<128, true, false, true, true, false, true, false, false>
      <<<dim3(1024, 1), 256, 0, stream>>>(
          L2OUT, WTH + WT_GW2, WTL + WT_GW2, nullptr, sums + SB1S,
          sums + SB1Q, 1.f / 131072.f, g_gam1, g_bet1, FEAT, 128, 128,
          nullptr, sums + SB2S, sums + SB2Q, nullptr, nullptr, nullptr);
  // c1 = relu(bn2(feat)) @ conv1_w + b
  gemm_mfma<128, true, true, true, false, false, false, false, false>
      <<<dim3(64, 1), 256, 0, stream>>>(
          FEAT, WTH + WT_C1, WTL + WT_C1, conv1_b, sums + SB2S, sums + SB2Q,
          1.f / 131072.f, g_gam2, g_bet2, C1F, 128, 128, nullptr, sums + SC1S,
          sums + SC1Q, nullptr, nullptr, nullptr);
  // c2 = relu(bn(c1)) @ conv2_w + b
  gemm_mfma<128, true, true, true, false, false, false, false, false>
      <<<dim3(64, 1), 256, 0, stream>>>(
          C1F, WTH + WT_C2, WTL + WT_C2, conv2_b, sums + SC1S, sums + SC1Q,
          1.f / 8192.f, bn1_g, bn1_b, C2F, 128, 128, nullptr, sums + SC2S,
          sums + SC2Q, nullptr, nullptr, nullptr);
  // net/clip = relu(bn(c2)) @ conv3_w + b  (N padded 384, nout=325)
  gemm_mfma<128, true, true, false, false, true, false, false, false>
      <<<dim3(64, 3), 256, 0, stream>>>(
          C2F, WTH + WT_C3, WTL + WT_C3, conv3_b, sums + SC2S, sums + SC2Q,
          1.f / 8192.f, bn2_g, bn2_b, net, 384, 325, CLIPF, nullptr, nullptr,
          nullptr, nullptr, nullptr);
  // h0 = clip_in @ h_w0 + b
  gemm_mfma<256, false, true, true, false, false, false, false, false>
      <<<dim3(64, 4), 256, 0, stream>>>(
          CLIPF, WTH + WT_H0, WTL + WT_H0, h_b0, nullptr, nullptr, 0.f,
          nullptr, nullptr, H0F, 512, 512, nullptr, sums + SH0S, sums + SH0Q,
          nullptr, nullptr, nullptr);
  // h1 = relu(bn(h0)) @ h_w1 + b
  gemm_mfma<512, true, true, true, false, false, false, false, false>
      <<<dim3(64, 4), 256, 0, stream>>>(
          H0F, WTH + WT_H1, WTL + WT_H1, h_b1, sums + SH0S, sums + SH0Q,
          1.f / 8192.f, h_g0, h_be0, H1F, 512, 512, nullptr, sums + SH1S,
          sums + SH1Q, nullptr, nullptr, nullptr);
  // q = relu(bn(h1)) @ h_w2 + b
  gemm_mfma<512, true, true, false, false, false, false, false, false>
      <<<dim3(64, 4), 256, 0, stream>>>(
          H1F, WTH + WT_H2, WTL + WT_H2, h_b2, sums + SH1S, sums + SH1Q,
          1.f / 8192.f, h_g1, h_be1, QF, 512, 512, nullptr, nullptr, nullptr,
          nullptr, nullptr, nullptr);
  final2<<<128, 512, 0, stream>>>(net, QF, tn, out);
}

// Round 11
// 786.875 us; speedup vs baseline: 1.0656x; 1.0656x over previous
//
#include <hip/hip_runtime.h>
#include <hip/hip_bf16.h>
#include <cstdint>
#include <cstddef>

#define Bb 16
#define Kk 2048
#define Pp 512
#define Ss 16
#define Cc 256

typedef __attribute__((ext_vector_type(8))) short bf16x8;
typedef __attribute__((ext_vector_type(4))) float f32x4;
typedef float v2f __attribute__((ext_vector_type(2)));

__device__ __forceinline__ unsigned short f2bf(float x) {  // RNE
  unsigned u = __float_as_uint(x);
  u = (u + 0x7FFF + ((u >> 16) & 1)) >> 16;
  return (unsigned short)u;
}
__device__ __forceinline__ float bf2f(unsigned short s) {
  return __uint_as_float((unsigned)s << 16);
}
// truncation split: x ~= hi + lo with |x-hi-lo| <= 2^-16 |x|
__device__ __forceinline__ void split2(float x, short& h, short& l) {
  unsigned u = __float_as_uint(x);
  h = (short)(u >> 16);
  float r = x - __uint_as_float(u & 0xFFFF0000u);
  l = (short)(__float_as_uint(r) >> 16);
}

// ---------------- workspace layout (bytes) ----------------
static constexpr size_t OFF_TNORM = 0;                          // 20480
static constexpr size_t OFF_SUMS  = 20480;                      // 16384
static constexpr size_t OFF_INDS  = 36864;                      // 32768
static constexpr size_t OFF_IDXL  = 69632;                      // 524288
static constexpr size_t OFF_GX    = 593920;                     // 1572864
static constexpr size_t OFF_F1    = 2166784;                    // 16777216 f32
static constexpr size_t OFF_BIGA  = 18944000;                   // 67108864
static constexpr size_t OFF_BIGB  = 86052864;                   // 67108864
static constexpr size_t OFF_NET   = 153161728;                  // 2260992 f32 (8192x69)
static constexpr size_t OFF_WTH   = 155422720;                  // 1540096 bf16
static constexpr size_t OFF_WTL   = 156962816;                  // 1540096 bf16
// BIGA: L2OUT bf16 (0..33.5M, dead after L3); QF f32 (0..16.7M, from h2 on)
// BIGB: FEAT +0 (4M) | C1F +4M | C2F +8M | CLIPF +12M (8M) | H0F +20M (16M)
//       | H1F +36M (16M)

// Wt element offsets ([N][K] row-major bf16)
#define WT_GW1 0
#define WT_GW2 16384
#define WT_C1  32768
#define WT_C2  49152
#define WT_H0  65536
#define WT_H1  196608
#define WT_H2  458752
#define WT_C3  720896   // 384x128 (N padded, rows >=325 zero)

// sum-slot float offsets inside OFF_SUMS
#define SB0S 0
#define SB0Q 128
#define SB1S 256
#define SB1Q 384
#define SB2S 512
#define SB2Q 640
#define SC1S 768
#define SC1Q 896
#define SC2S 1024
#define SC2Q 1152
#define SH0S 1280
#define SH0Q 1792
#define SH1S 2304
#define SH1Q 2816

template <int CTRL>
__device__ __forceinline__ float fmax_dpp(float v) {
  int o = __builtin_amdgcn_update_dpp(0, __float_as_int(v), CTRL, 0xF, 0xF, true);
  return fmaxf(v, __int_as_float(o));
}

// fused: fps (0..15) | F1 gemm (16..527) | tnorm (528) | wprep (529..628)
__global__ __launch_bounds__(256, 1) void fused_pre(
    const float* __restrict__ xyz, int* __restrict__ inds,
    const float* __restrict__ features, const float* __restrict__ g_w0,
    float* __restrict__ F1, const float* __restrict__ text,
    float* __restrict__ tn, const float* __restrict__ g_w1,
    const float* __restrict__ g_w2, const float* __restrict__ conv1_w,
    const float* __restrict__ conv2_w, const float* __restrict__ conv3_w,
    const float* __restrict__ h_w0, const float* __restrict__ h_w1,
    const float* __restrict__ h_w2, unsigned short* __restrict__ wth,
    unsigned short* __restrict__ wtl) {
  __shared__ __align__(16) float smem[8208];
  const int tid = threadIdx.x;

  if (blockIdx.x < 16) {
    // ===== FPS: 4 waves, thread-major k = tid*8+j ==========================
    // Mailbox carries winner {key, x,y,z}. Winner coords are extracted with
    // COMPILE-TIME indices only (tree-carry) -- runtime-indexed register
    // arrays would spill to scratch (R9 regression, Rule #20).
    #pragma clang fp contract(off)
    const int b = blockIdx.x;
    unsigned long long (*redk)[4] = (unsigned long long(*)[4])smem;  // 16 f
    float4 (*redc)[4] = (float4(*)[4])(smem + 16);                   // 32 f
    const float* base = xyz + (size_t)b * Kk * 3;
    if (tid == 0) inds[b * Pp] = 0;
    v2f PX[4], PY[4], PZ[4], DM[4];
    {
      const float* pb = base + tid * 24;
      float4 f0 = *(const float4*)(pb + 0);
      float4 f1 = *(const float4*)(pb + 4);
      float4 f2 = *(const float4*)(pb + 8);
      float4 f3 = *(const float4*)(pb + 12);
      float4 f4 = *(const float4*)(pb + 16);
      float4 f5 = *(const float4*)(pb + 20);
      PX[0] = (v2f){f0.x, f0.w}; PY[0] = (v2f){f0.y, f1.x}; PZ[0] = (v2f){f0.z, f1.y};
      PX[1] = (v2f){f1.z, f2.y}; PY[1] = (v2f){f1.w, f2.z}; PZ[1] = (v2f){f2.x, f2.w};
      PX[2] = (v2f){f3.x, f3.w}; PY[2] = (v2f){f3.y, f4.x}; PZ[2] = (v2f){f3.z, f4.y};
      PX[3] = (v2f){f4.z, f5.y}; PY[3] = (v2f){f4.w, f5.z}; PZ[3] = (v2f){f5.x, f5.w};
      #pragma unroll
      for (int p = 0; p < 4; p++) DM[p] = (v2f){1e10f, 1e10f};
    }
    // seed: point 0 (inds[0] = 0)
    float lx = base[0], ly = base[1], lz = base[2];
    const int lane = tid & 63, wid = tid >> 6;
    for (int it = 1; it < Pp; ++it) {
      v2f vlx = {lx, lx}, vly = {ly, ly}, vlz = {lz, lz};
      float pf[4], pcx[4], pcy[4], pcz[4];
      int pk_[4];
      #pragma unroll
      for (int p = 0; p < 4; p++) {
        v2f dx = PX[p] - vlx, dy = PY[p] - vly, dz = PZ[p] - vlz;
        v2f d = (dx * dx + dy * dy) + dz * dz;  // contract off: exact mul/add
        v2f m2 = __builtin_elementwise_min(DM[p], d);
        DM[p] = m2;
        bool t = m2.y > m2.x;                 // strict >: prefer lower index
        pf[p] = t ? m2.y : m2.x;
        pk_[p] = 2 * p + (t ? 1 : 0);
        pcx[p] = t ? PX[p].y : PX[p].x;       // compile-time p
        pcy[p] = t ? PY[p].y : PY[p].x;
        pcz[p] = t ? PZ[p].y : PZ[p].x;
      }
      // 2-level tree; carry key AND coords (all static indices)
      bool t01 = pf[1] > pf[0];
      float f01 = t01 ? pf[1] : pf[0];
      int k01 = t01 ? pk_[1] : pk_[0];
      float cx01 = t01 ? pcx[1] : pcx[0];
      float cy01 = t01 ? pcy[1] : pcy[0];
      float cz01 = t01 ? pcz[1] : pcz[0];
      bool t23 = pf[3] > pf[2];
      float f23 = t23 ? pf[3] : pf[2];
      int k23 = t23 ? pk_[3] : pk_[2];
      float cx23 = t23 ? pcx[3] : pcx[2];
      float cy23 = t23 ? pcy[3] : pcy[2];
      float cz23 = t23 ? pcz[3] : pcz[2];
      bool tt = f23 > f01;
      float bf = tt ? f23 : f01;
      int bk = tt ? k23 : k01;
      float wx = tt ? cx23 : cx01;
      float wy = tt ? cy23 : cy01;
      float wz = tt ? cz23 : cz01;
      float g = bf;
      g = fmax_dpp<0xB1>(g);   // xor 1
      g = fmax_dpp<0x4E>(g);   // xor 2
      g = fmax_dpp<0x141>(g);  // xor 7
      g = fmax_dpp<0x140>(g);  // xor 15
      g = fmax_dpp<0x142>(g);  // row_bcast15
      g = fmax_dpp<0x143>(g);  // row_bcast31 -> lane63 = wave max
      float gs = __uint_as_float(
          (unsigned)__builtin_amdgcn_readlane(__float_as_int(g), 63));
      unsigned long long msk = __ballot(bf == gs);
      int src = __builtin_ctzll(msk);  // lowest lane = lowest k (thread-major)
      if (lane == src) {
        int kk = (tid << 3) | bk;
        redk[it & 1][wid] = ((unsigned long long)__float_as_uint(gs) << 32) |
                            (unsigned)(~(unsigned)kk);
        redc[it & 1][wid] = make_float4(wx, wy, wz, 0.f);
      }
      __syncthreads();
      unsigned long long q0 = redk[it & 1][0], q1 = redk[it & 1][1];
      unsigned long long q2 = redk[it & 1][2], q3 = redk[it & 1][3];
      float4 c0 = redc[it & 1][0], c1 = redc[it & 1][1];
      float4 c2 = redc[it & 1][2], c3 = redc[it & 1][3];
      bool s01 = q0 > q1;
      unsigned long long m01 = s01 ? q0 : q1;
      float4 cc01 = s01 ? c0 : c1;
      bool s23 = q2 > q3;
      unsigned long long m23 = s23 ? q2 : q3;
      float4 cc23 = s23 ? c2 : c3;
      bool sw = m23 > m01;
      unsigned long long mm = sw ? m23 : m01;
      float4 cw = sw ? cc23 : cc01;
      lx = cw.x; ly = cw.y; lz = cw.z;
      if (tid == 0) inds[b * Pp + it] = (int)(~(unsigned)mm);
    }
  } else if (blockIdx.x == 528) {
    int w = tid >> 6, lane = tid & 63;
    for (int r = w; r < 10; r += 4) {
      const float* rw = text + (size_t)r * 512;
      float v[8];
      float ss = 0.f;
      #pragma unroll
      for (int u = 0; u < 8; u++) { v[u] = rw[lane + 64 * u]; ss += v[u] * v[u]; }
      #pragma unroll
      for (int off = 32; off; off >>= 1) ss += __shfl_xor(ss, off, 64);
      float nrm = sqrtf(ss);
      #pragma unroll
      for (int u = 0; u < 8; u++)
        tn[(size_t)r * 512 + lane + 64 * u] = v[u] / nrm;
    }
  } else if (blockIdx.x >= 529) {
    // ===== weight transpose + RNE bf16 split (parallel, 100 blocks) =======
    int wb = blockIdx.x - 529;
    const float* W;
    int K, N, NS, nblk, pidx;
    unsigned short *dh, *dl;
    if (wb < 4)       { W = g_w1;    K = 128; N = 128; NS = 128; dh = wth + WT_GW1; dl = wtl + WT_GW1; nblk = 4;  pidx = wb; }
    else if (wb < 8)  { W = g_w2;    K = 128; N = 128; NS = 128; dh = wth + WT_GW2; dl = wtl + WT_GW2; nblk = 4;  pidx = wb - 4; }
    else if (wb < 12) { W = conv1_w; K = 128; N = 128; NS = 128; dh = wth + WT_C1;  dl = wtl + WT_C1;  nblk = 4;  pidx = wb - 8; }
    else if (wb < 16) { W = conv2_w; K = 128; N = 128; NS = 128; dh = wth + WT_C2;  dl = wtl + WT_C2;  nblk = 4;  pidx = wb - 12; }
    else if (wb < 32) { W = h_w0;    K = 256; N = 512; NS = 512; dh = wth + WT_H0;  dl = wtl + WT_H0;  nblk = 16; pidx = wb - 16; }
    else if (wb < 64) { W = h_w1;    K = 512; N = 512; NS = 512; dh = wth + WT_H1;  dl = wtl + WT_H1;  nblk = 32; pidx = wb - 32; }
    else if (wb < 96) { W = h_w2;    K = 512; N = 512; NS = 512; dh = wth + WT_H2;  dl = wtl + WT_H2;  nblk = 32; pidx = wb - 64; }
    else              { W = conv3_w; K = 128; N = 384; NS = 325; dh = wth + WT_C3;  dl = wtl + WT_C3;  nblk = 4;  pidx = wb - 96; }
    for (int idx = pidx * 256 + tid; idx < K * N; idx += nblk * 256) {
      int k = idx / N, n = idx - k * N;
      float w = (n < NS) ? W[k * NS + n] : 0.f;
      unsigned short hi = f2bf(w);
      unsigned short lo = f2bf(w - bf2f(hi));
      dh[n * K + k] = hi;
      dl[n * K + k] = lo;
    }
  } else {
    // ===== F1 = feats_kc @ g_w0[3:,:]  (32768 x 256 x 128) ================
    float (*a_t)[68] = (float(*)[68])smem;
    float (*b_t)[128] = (float(*)[128])(smem + 32 * 68);
    const float* W = g_w0 + 3 * 128;
    const int m0 = (blockIdx.x - 16) * 64;
    float acc[4][8];
    #pragma unroll
    for (int i = 0; i < 4; i++)
      #pragma unroll
      for (int j = 0; j < 8; j++) acc[i][j] = 0.f;
    const int ty = tid >> 4, tx = tid & 15;
    const int lr = tid & 63, wv = tid >> 6;
    const int bb = m0 >> 11, k0 = m0 & 2047;
    const float* fb = features + (size_t)bb * (Cc * Kk);
    for (int c0 = 0; c0 < 256; c0 += 32) {
      #pragma unroll
      for (int i = 0; i < 8; i++) {
        int c = c0 + wv + 4 * i;
        a_t[wv + 4 * i][lr] = fb[(size_t)c * Kk + k0 + lr];
      }
      #pragma unroll
      for (int p = 0; p < 4; p++) {
        int cc = p * 8 + (tid >> 5);
        int nl = (tid & 31) * 4;
        *(float4*)&b_t[cc][nl] = *(const float4*)&W[(size_t)(c0 + cc) * 128 + nl];
      }
      __syncthreads();
      #pragma unroll
      for (int kk = 0; kk < 32; kk++) {
        float4 av = *(const float4*)&a_t[kk][ty * 4];
        float4 b0 = *(const float4*)&b_t[kk][tx * 4];
        float4 b1 = *(const float4*)&b_t[kk][tx * 4 + 64];
        float ap[4] = {av.x, av.y, av.z, av.w};
        float bq0[4] = {b0.x, b0.y, b0.z, b0.w};
        float bq1[4] = {b1.x, b1.y, b1.z, b1.w};
        #pragma unroll
        for (int i = 0; i < 4; i++) {
          #pragma unroll
          for (int u = 0; u < 4; u++) {
            acc[i][u] = fmaf(ap[i], bq0[u], acc[i][u]);
            acc[i][4 + u] = fmaf(ap[i], bq1[u], acc[i][4 + u]);
          }
        }
      }
      __syncthreads();
    }
    #pragma unroll
    for (int i = 0; i < 4; i++) {
      size_t mrow = (size_t)(m0 + ty * 4 + i);
      #pragma unroll
      for (int gq = 0; gq < 2; gq++) {
        float4 v4 = make_float4(acc[i][gq * 4], acc[i][gq * 4 + 1],
                                acc[i][gq * 4 + 2], acc[i][gq * 4 + 3]);
        *(float4*)&F1[mrow * 128 + gq * 64 + tx * 4] = v4;
      }
    }
  }
}

// -------- neighbor selection + bn0 stats (xyz staged in LDS) --------
__global__ __launch_bounds__(256) void neigh_k(
    const float* __restrict__ xyz, const int* __restrict__ inds,
    const float* __restrict__ F1, const float* __restrict__ g_w0,
    int* __restrict__ idxl, float* __restrict__ gx, float* __restrict__ s0,
    float* __restrict__ q0) {
  __shared__ float rs[128], rq[128];
  __shared__ __align__(16) float4 pts[Kk];  // 32KB, all 4 waves same batch
  const int tid = threadIdx.x;
  if (tid < 128) { rs[tid] = 0.f; rq[tid] = 0.f; }
  int widx = blockIdx.x * 4 + (tid >> 6);
  int lane = tid & 63;
  int b = widx >> 9;
  const float* base = xyz + (size_t)b * Kk * 3;
  for (int i = tid; i < Kk; i += 256)
    pts[i] = make_float4(base[3 * i], base[3 * i + 1], base[3 * i + 2], 0.f);
  __syncthreads();
  int q = inds[widx];
  float4 Q = pts[q];
  float qx = Q.x, qy = Q.y, qz = Q.z;
  int cnt = 0;
  int myk = 0;
  for (int ch = 0; ch < 32 && cnt < Ss; ch++) {
    float4 P = pts[ch * 64 + lane];
    float dx = P.x - qx;
    float dy = P.y - qy;
    float dz = P.z - qz;
    float d2 = __fadd_rn(__fadd_rn(__fmul_rn(dx, dx), __fmul_rn(dy, dy)),
                         __fmul_rn(dz, dz));
    unsigned long long m = __ballot(d2 < 0.09f);
    while (m && cnt < Ss) {
      int t = __builtin_ctzll(m);
      if (lane == cnt) myk = ch * 64 + t;
      cnt++;
      m &= m - 1;
    }
  }
  int first = __shfl(myk, 0, 64);
  int kksel = 0;
  float g0r = 0.f, g1r = 0.f, g2r = 0.f;
  if (lane < Ss) {
    int kk = (lane < cnt) ? myk : first;
    kksel = kk;
    float4 P = pts[kk];
    g0r = (P.x - qx) / 0.3f;
    g1r = (P.y - qy) / 0.3f;
    g2r = (P.z - qz) / 0.3f;
    size_t o = (size_t)widx * Ss + lane;
    idxl[o] = kk;
    gx[o * 3 + 0] = g0r;
    gx[o * 3 + 1] = g1r;
    gx[o * 3 + 2] = g2r;
  }
  // ---- bn0 stats over the 16 gathered rows (cols: lane and lane+64) ----
  const float* f1b = F1 + (size_t)(b << 11) * 128;
  float wa0 = g_w0[lane], wa1 = g_w0[128 + lane], wa2 = g_w0[256 + lane];
  float wb0 = g_w0[64 + lane], wb1 = g_w0[192 + lane], wb2 = g_w0[320 + lane];
  float sa = 0.f, qa = 0.f, sb = 0.f, qb = 0.f;
  #pragma unroll
  for (int s = 0; s < Ss; s++) {
    int bidx = __shfl(kksel, s, 64);
    float gg0 = __shfl(g0r, s, 64);
    float gg1 = __shfl(g1r, s, 64);
    float gg2 = __shfl(g2r, s, 64);
    const float* fr = f1b + (size_t)bidx * 128;
    float va = fr[lane] + gg0 * wa0 + gg1 * wa1 + gg2 * wa2;
    float vb = fr[64 + lane] + gg0 * wb0 + gg1 * wb1 + gg2 * wb2;
    sa += va; qa += va * va;
    sb += vb; qb += vb * vb;
  }
  atomicAdd(&rs[lane], sa);
  atomicAdd(&rq[lane], qa);
  atomicAdd(&rs[64 + lane], sb);
  atomicAdd(&rq[64 + lane], qb);
  __syncthreads();
  if (tid < 128) {
    atomicAdd(&s0[tid], rs[tid]);
    atomicAdd(&q0[tid], rq[tid]);
  }
}

// ------- split-bf16 MFMA GEMM: out = act_in(A) @ (Wh+Wl)^T (+bias) ---------
// GATHER: A[row] = F1[gidx[row]] + gx(row).w_xyz  (inline gather, f32 src)
// ABF16 : A stored bf16. OBF16: store bf16.
// OMAX  : emit per-16-row-group max. WCLIP: split cols -> net / clipf.
template <int KD, bool INBN, bool HASBIAS, bool OSUM, bool OMAX, bool WCLIP,
          bool ABF16, bool GATHER, bool OBF16>
__global__ __launch_bounds__(256, 2) void gemm_mfma(
    const void* __restrict__ A, const unsigned short* __restrict__ Wh,
    const unsigned short* __restrict__ Wl, const float* __restrict__ bias,
    const float* __restrict__ isum, const float* __restrict__ isq,
    float inv_cnt, const float* __restrict__ gamma,
    const float* __restrict__ beta, void* __restrict__ outp, int N, int nout,
    float* __restrict__ clipf, float* __restrict__ osum,
    float* __restrict__ osq, const int* __restrict__ idxl,
    const float* __restrict__ gxv, const float* __restrict__ w0raw) {
  __shared__ float sc[INBN ? KD : 1];
  __shared__ float sh[INBN ? KD : 1];
  __shared__ float red_s[OSUM ? 128 : 1];
  __shared__ float red_q[OSUM ? 128 : 1];
  const int tid = threadIdx.x;
  if (INBN) {
    for (int c = tid; c < KD; c += 256) {
      float mean = isum[c] * inv_cnt;
      float var = isq[c] * inv_cnt - mean * mean;
      float is_ = rsqrtf(var + 1e-5f);
      float scl = gamma[c] * is_;
      sc[c] = scl;
      sh[c] = beta[c] - mean * scl;
    }
  }
  if (OSUM && tid < 128) { red_s[tid] = 0.f; red_q[tid] = 0.f; }
  __syncthreads();
  const int wave = tid >> 6, lane = tid & 63;
  const int wm = wave >> 1, wn = wave & 1;
  const int r = lane & 15, g = lane >> 4;
  const size_t m0 = (size_t)blockIdx.x * 128 + wm * 64;
  const int n0 = blockIdx.y * 128 + wn * 64;

  const float* Af = (const float*)A;
  const unsigned short* Ab = (const unsigned short*)A;

  size_t gi[4];
  float gx0[4], gx1[4], gx2[4];
  if (GATHER) {
    #pragma unroll
    for (int mf = 0; mf < 4; mf++) {
      int row = (int)m0 + mf * 16 + r;
      gi[mf] = ((size_t)((row >> 13) << 11) + idxl[row]) * 128;
      gx0[mf] = gxv[3 * (size_t)row];
      gx1[mf] = gxv[3 * (size_t)row + 1];
      gx2[mf] = gxv[3 * (size_t)row + 2];
    }
  }

  f32x4 acc[4][4] = {};
  for (int ks = 0; ks < KD / 32; ks++) {
    const int kb = ks * 32 + g * 8;
    bf16x8 bh[4], bl[4];
    #pragma unroll
    for (int nf = 0; nf < 4; nf++) {
      bh[nf] = *(const bf16x8*)&Wh[(size_t)(n0 + nf * 16 + r) * KD + kb];
      bl[nf] = *(const bf16x8*)&Wl[(size_t)(n0 + nf * 16 + r) * KD + kb];
    }
    float s8[8], h8[8];
    if (INBN) {
      #pragma unroll
      for (int j = 0; j < 8; j++) { s8[j] = sc[kb + j]; h8[j] = sh[kb + j]; }
    }
    float wxr[8], wyr[8], wzr[8];
    if (GATHER) {
      float4 a0 = *(const float4*)&w0raw[kb];
      float4 a1 = *(const float4*)&w0raw[kb + 4];
      float4 b0 = *(const float4*)&w0raw[128 + kb];
      float4 b1 = *(const float4*)&w0raw[128 + kb + 4];
      float4 c0 = *(const float4*)&w0raw[256 + kb];
      float4 c1 = *(const float4*)&w0raw[256 + kb + 4];
      wxr[0]=a0.x; wxr[1]=a0.y; wxr[2]=a0.z; wxr[3]=a0.w;
      wxr[4]=a1.x; wxr[5]=a1.y; wxr[6]=a1.z; wxr[7]=a1.w;
      wyr[0]=b0.x; wyr[1]=b0.y; wyr[2]=b0.z; wyr[3]=b0.w;
      wyr[4]=b1.x; wyr[5]=b1.y; wyr[6]=b1.z; wyr[7]=b1.w;
      wzr[0]=c0.x; wzr[1]=c0.y; wzr[2]=c0.z; wzr[3]=c0.w;
      wzr[4]=c1.x; wzr[5]=c1.y; wzr[6]=c1.z; wzr[7]=c1.w;
    }
    #pragma unroll
    for (int mf = 0; mf < 4; mf++) {
      float xv[8];
      if (GATHER) {
        const float* fp = Af + gi[mf] + kb;
        float4 x0 = *(const float4*)fp;
        float4 x1 = *(const float4*)(fp + 4);
        xv[0]=x0.x; xv[1]=x0.y; xv[2]=x0.z; xv[3]=x0.w;
        xv[4]=x1.x; xv[5]=x1.y; xv[6]=x1.z; xv[7]=x1.w;
        #pragma unroll
        for (int j = 0; j < 8; j++)
          xv[j] += gx0[mf] * wxr[j] + gx1[mf] * wyr[j] + gx2[mf] * wzr[j];
      } else if (ABF16) {
        bf16x8 rawv = *(const bf16x8*)&Ab[(m0 + mf * 16 + r) * KD + kb];
        #pragma unroll
        for (int j = 0; j < 8; j++) xv[j] = bf2f((unsigned short)rawv[j]);
      } else {
        const float* ap = Af + (m0 + mf * 16 + r) * KD + kb;
        float4 x0 = *(const float4*)ap;
        float4 x1 = *(const float4*)(ap + 4);
        xv[0]=x0.x; xv[1]=x0.y; xv[2]=x0.z; xv[3]=x0.w;
        xv[4]=x1.x; xv[5]=x1.y; xv[6]=x1.z; xv[7]=x1.w;
      }
      bf16x8 ah, al;
      #pragma unroll
      for (int j = 0; j < 8; j++) {
        float x = xv[j];
        if (INBN) x = fmaxf(fmaf(x, s8[j], h8[j]), 0.f);
        short hh, ll;
        split2(x, hh, ll);
        ah[j] = hh;
        al[j] = ll;
      }
      #pragma unroll
      for (int nf = 0; nf < 4; nf++) {
        acc[mf][nf] = __builtin_amdgcn_mfma_f32_16x16x32_bf16(
            ah, bh[nf], acc[mf][nf], 0, 0, 0);
        acc[mf][nf] = __builtin_amdgcn_mfma_f32_16x16x32_bf16(
            al, bh[nf], acc[mf][nf], 0, 0, 0);
        acc[mf][nf] = __builtin_amdgcn_mfma_f32_16x16x32_bf16(
            ah, bl[nf], acc[mf][nf], 0, 0, 0);
      }
    }
  }
  float bv[4];
  if (HASBIAS) {
    #pragma unroll
    for (int nf = 0; nf < 4; nf++) {
      int col = n0 + nf * 16 + r;
      bv[nf] = (!WCLIP || col < nout) ? bias[col] : 0.f;
    }
  }
  float ps[4] = {0.f, 0.f, 0.f, 0.f}, pq[4] = {0.f, 0.f, 0.f, 0.f};
  #pragma unroll
  for (int mf = 0; mf < 4; mf++) {
    float mx[4];
    #pragma unroll
    for (int nf = 0; nf < 4; nf++) {
      float vmax = -1e30f;
      #pragma unroll
      for (int j = 0; j < 4; j++) {
        float v = acc[mf][nf][j];
        if (HASBIAS) v += bv[nf];
        size_t row = m0 + mf * 16 + g * 4 + j;
        int col = n0 + nf * 16 + r;
        if (OSUM) { ps[nf] += v; pq[nf] += v * v; }
        if (OMAX) {
          vmax = fmaxf(vmax, v);
        } else if (WCLIP) {
          if (col < 69) ((float*)outp)[row * 69 + col] = v;
          else if (col < nout) clipf[row * 256 + (col - 69)] = v;
        } else if (OBF16) {
          ((unsigned short*)outp)[row * N + col] = f2bf(v);
        } else {
          ((float*)outp)[row * N + col] = v;
        }
      }
      mx[nf] = vmax;
    }
    if (OMAX) {
      #pragma unroll
      for (int nf = 0; nf < 4; nf++) {
        float m = mx[nf];
        m = fmaxf(m, __shfl_xor(m, 16, 64));
        m = fmaxf(m, __shfl_xor(m, 32, 64));
        if (g == 0) {
          size_t bq = (m0 >> 4) + mf;
          ((float*)outp)[bq * 128 + n0 + nf * 16 + r] = m;
        }
      }
    }
  }
  if (OSUM) {
    #pragma unroll
    for (int nf = 0; nf < 4; nf++) {
      #pragma unroll
      for (int off = 16; off < 64; off <<= 1) {
        ps[nf] += __shfl_xor(ps[nf], off, 64);
        pq[nf] += __shfl_xor(pq[nf], off, 64);
      }
    }
    if (lane < 16) {
      #pragma unroll
      for (int nf = 0; nf < 4; nf++) {
        int lcol = wn * 64 + nf * 16 + r;
        atomicAdd(&red_s[lcol], ps[nf]);
        atomicAdd(&red_q[lcol], pq[nf]);
      }
    }
    __syncthreads();
    if (tid < 128) {
      atomicAdd(&osum[blockIdx.y * 128 + tid], red_s[tid]);
      atomicAdd(&osq[blockIdx.y * 128 + tid], red_q[tid]);
    }
  }
}

// ---------------- final: q-norm, logits, coalesced transpose-assemble -------
__global__ __launch_bounds__(512) void final2(const float* __restrict__ net,
                                              const float* __restrict__ qbuf,
                                              const float* __restrict__ tn,
                                              float* __restrict__ out) {
  __shared__ float tile[79][65];
  const int blk = blockIdx.x;
  const int tid = threadIdx.x;
  const int r = tid >> 3, oct = tid & 7;
  const int row = blk * 64 + r;
  const int b = (blk * 64) >> 9, p0 = (blk * 64) & 511;

  const float* qr = qbuf + (size_t)row * 512 + oct * 64;
  float4 q4[16];
  #pragma unroll
  for (int i = 0; i < 16; i++) q4[i] = *(const float4*)(qr + 4 * i);
  float ss = 0.f;
  float dot[10];
  #pragma unroll
  for (int t = 0; t < 10; t++) dot[t] = 0.f;
  #pragma unroll
  for (int i = 0; i < 16; i++) {
    float4 a = q4[i];
    ss += a.x * a.x + a.y * a.y + a.z * a.z + a.w * a.w;
    #pragma unroll
    for (int t = 0; t < 10; t++) {
      float4 b4 = *(const float4*)(tn + (size_t)t * 512 + oct * 64 + i * 4);
      dot[t] += a.x * b4.x + a.y * b4.y + a.z * b4.z + a.w * b4.w;
    }
  }
  #pragma unroll
  for (int off = 1; off < 8; off <<= 1) {
    ss += __shfl_xor(ss, off, 8);
    #pragma unroll
    for (int t = 0; t < 10; t++) dot[t] += __shfl_xor(dot[t], off, 8);
  }
  if (oct == 0) {
    float inv = rsqrtf(ss) * (1.f / 0.07f);
    #pragma unroll
    for (int t = 0; t < 10; t++) tile[69 + t][r] = dot[t] * inv;
  }
  for (int idx = tid; idx < 64 * 69; idx += 512) {
    int r2 = idx / 69, ch = idx - 69 * r2;
    tile[ch][r2] = net[(size_t)(blk * 64 + r2) * 69 + ch];
  }
  __syncthreads();
  for (int idx = tid; idx < 79 * 64; idx += 512) {
    int ch = idx >> 6, rr = idx & 63;
    out[((size_t)b * 79 + ch) * 512 + p0 + rr] = tile[ch][rr];
  }
}

extern "C" void kernel_launch(void* const* d_in, const int* in_sizes, int n_in,
                              void* d_out, int out_size, void* d_ws,
                              size_t ws_size, hipStream_t stream) {
  const float* xyz = (const float*)d_in[0];
  const float* features = (const float*)d_in[1];
  const float* text = (const float*)d_in[2];
  const float* g_w0 = (const float*)d_in[3];
  const float* g_w1 = (const float*)d_in[4];
  const float* g_w2 = (const float*)d_in[5];
  const float* g_gam0 = (const float*)d_in[6];
  const float* g_bet0 = (const float*)d_in[7];
  const float* g_gam1 = (const float*)d_in[8];
  const float* g_bet1 = (const float*)d_in[9];
  const float* g_gam2 = (const float*)d_in[10];
  const float* g_bet2 = (const float*)d_in[11];
  const float* conv1_w = (const float*)d_in[12];
  const float* conv1_b = (const float*)d_in[13];
  const float* bn1_g = (const float*)d_in[14];
  const float* bn1_b = (const float*)d_in[15];
  const float* conv2_w = (const float*)d_in[16];
  const float* conv2_b = (const float*)d_in[17];
  const float* bn2_g = (const float*)d_in[18];
  const float* bn2_b = (const float*)d_in[19];
  const float* conv3_w = (const float*)d_in[20];
  const float* conv3_b = (const float*)d_in[21];
  const float* h_w0 = (const float*)d_in[22];
  const float* h_b0 = (const float*)d_in[23];
  const float* h_g0 = (const float*)d_in[24];
  const float* h_be0 = (const float*)d_in[25];
  const float* h_w1 = (const float*)d_in[26];
  const float* h_b1 = (const float*)d_in[27];
  const float* h_g1 = (const float*)d_in[28];
  const float* h_be1 = (const float*)d_in[29];
  const float* h_w2 = (const float*)d_in[30];
  const float* h_b2 = (const float*)d_in[31];
  float* out = (float*)d_out;
  char* ws = (char*)d_ws;

  float* tn = (float*)(ws + OFF_TNORM);
  float* sums = (float*)(ws + OFF_SUMS);
  int* inds = (int*)(ws + OFF_INDS);
  int* idxl = (int*)(ws + OFF_IDXL);
  float* gx = (float*)(ws + OFF_GX);
  float* F1 = (float*)(ws + OFF_F1);
  unsigned short* L2OUT = (unsigned short*)(ws + OFF_BIGA);
  float* QF = (float*)(ws + OFF_BIGA);
  float* FEAT = (float*)(ws + OFF_BIGB);
  float* C1F = (float*)(ws + OFF_BIGB + 4194304);
  float* C2F = (float*)(ws + OFF_BIGB + 8388608);
  float* CLIPF = (float*)(ws + OFF_BIGB + 12582912);
  float* H0F = (float*)(ws + OFF_BIGB + 20971520);
  float* H1F = (float*)(ws + OFF_BIGB + 37748736);
  float* net = (float*)(ws + OFF_NET);
  unsigned short* WTH = (unsigned short*)(ws + OFF_WTH);
  unsigned short* WTL = (unsigned short*)(ws + OFF_WTL);

  hipMemsetAsync(sums, 0, 16384, stream);
  fused_pre<<<629, 256, 0, stream>>>(xyz, inds, features, g_w0, F1, text, tn,
                                     g_w1, g_w2, conv1_w, conv2_w, conv3_w,
                                     h_w0, h_w1, h_w2, WTH, WTL);
  // neighbor selection + bn0 stats
  neigh_k<<<2048, 256, 0, stream>>>(xyz, inds, F1, g_w0, idxl, gx,
                                    sums + SB0S, sums + SB0Q);
  // L2 = relu(bn0(gather(F1)+gx.w)) @ g_w1  (inline gather, bf16 out)
  gemm_mfma<128, true, false, true, false, false, false, true, true>
      <<<dim3(1024, 1), 256, 0, stream>>>(
          F1, WTH + WT_GW1, WTL + WT_GW1, nullptr, sums + SB0S, sums + SB0Q,
          1.f / 131072.f, g_gam0, g_bet0, L2OUT, 128, 128, nullptr,
          sums + SB1S, sums + SB1Q, idxl, gx, g_w0);
  // L3 = relu(bn1(L2)) @ g_w2, fused raw max over S=16 -> FEAT (+bn2 stats)
  gemm_mfma<128, true, false, true, true, false, true, false, false>
      <<<dim3(1024, 1), 256, 0, stream>>>(
          L2OUT, WTH + WT_GW2, WTL + WT_GW2, nullptr, sums + SB1S,
          sums + SB1Q, 1.f / 131072.f, g_gam1, g_bet1, FEAT, 128, 128,
          nullptr, sums + SB2S, sums + SB2Q, nullptr, nullptr, nullptr);
  // c1 = relu(bn2(feat)) @ conv1_w + b
  gemm_mfma<128, true, true, true, false, false, false, false, false>
      <<<dim3(64, 1), 256, 0, stream>>>(
          FEAT, WTH + WT_C1, WTL + WT_C1, conv1_b, sums + SB2S, sums + SB2Q,
          1.f / 131072.f, g_gam2, g_bet2, C1F, 128, 128, nullptr, sums + SC1S,
          sums + SC1Q, nullptr, nullptr, nullptr);
  // c2 = relu(bn(c1)) @ conv2_w + b
  gemm_mfma<128, true, true, true, false, false, false, false, false>
      <<<dim3(64, 1), 256, 0, stream>>>(
          C1F, WTH + WT_C2, WTL + WT_C2, conv2_b, sums + SC1S, sums + SC1Q,
          1.f / 8192.f, bn1_g, bn1_b, C2F, 128, 128, nullptr, sums + SC2S,
          sums + SC2Q, nullptr, nullptr, nullptr);
  // net/clip = relu(bn(c2)) @ conv3_w + b  (N padded 384, nout=325)
  gemm_mfma<128, true, true, false, false, true, false, false, false>
      <<<dim3(64, 3), 256, 0, stream>>>(
          C2F, WTH + WT_C3, WTL + WT_C3, conv3_b, sums + SC2S, sums + SC2Q,
          1.f / 8192.f, bn2_g, bn2_b, net, 384, 325, CLIPF, nullptr, nullptr,
          nullptr, nullptr, nullptr);
  // h0 = clip_in @ h_w0 + b
  gemm_mfma<256, false, true, true, false, false, false, false, false>
      <<<dim3(64, 4), 256, 0, stream>>>(
          CLIPF, WTH + WT_H0, WTL + WT_H0, h_b0, nullptr, nullptr, 0.f,
          nullptr, nullptr, H0F, 512, 512, nullptr, sums + SH0S, sums + SH0Q,
          nullptr, nullptr, nullptr);
  // h1 = relu(bn(h0)) @ h_w1 + b
  gemm_mfma<512, true, true, true, false, false, false, false, false>
      <<<dim3(64, 4), 256, 0, stream>>>(
          H0F, WTH + WT_H1, WTL + WT_H1, h_b1, sums + SH0S, sums + SH0Q,
          1.f / 8192.f, h_g0, h_be0, H1F, 512, 512, nullptr, sums + SH1S,
          sums + SH1Q, nullptr, nullptr, nullptr);
  // q = relu(bn(h1)) @ h_w2 + b
  gemm_mfma<512, true, true, false, false, false, false, false, false>
      <<<dim3(64, 4), 256, 0, stream>>>(
          H1F, WTH + WT_H2, WTL + WT_H2, h_b2, sums + SH1S, sums + SH1Q,
          1.f / 8192.f, h_g1, h_be1, QF, 512, 512, nullptr, nullptr, nullptr,
          nullptr, nullptr, nullptr);
  final2<<<128, 512, 0, stream>>>(net, QF, tn, out);
}

// Round 12
// 775.241 us; speedup vs baseline: 1.0816x; 1.0150x over previous
//
#include <hip/hip_runtime.h>
#include <hip/hip_bf16.h>
#include <cstdint>
#include <cstddef>

#define Bb 16
#define Kk 2048
#define Pp 512
#define Ss 16
#define Cc 256

typedef __attribute__((ext_vector_type(8))) short bf16x8;
typedef __attribute__((ext_vector_type(4))) float f32x4;
typedef float v2f __attribute__((ext_vector_type(2)));

__device__ __forceinline__ unsigned short f2bf(float x) {  // RNE
  unsigned u = __float_as_uint(x);
  u = (u + 0x7FFF + ((u >> 16) & 1)) >> 16;
  return (unsigned short)u;
}
__device__ __forceinline__ float bf2f(unsigned short s) {
  return __uint_as_float((unsigned)s << 16);
}
// truncation split: x ~= hi + lo with |x-hi-lo| <= 2^-16 |x|
__device__ __forceinline__ void split2(float x, short& h, short& l) {
  unsigned u = __float_as_uint(x);
  h = (short)(u >> 16);
  float r = x - __uint_as_float(u & 0xFFFF0000u);
  l = (short)(__float_as_uint(r) >> 16);
}

// ---------------- workspace layout (bytes) ----------------
static constexpr size_t OFF_TNORM = 0;                          // 20480
static constexpr size_t OFF_SUMS  = 20480;                      // 16384
static constexpr size_t OFF_INDS  = 36864;                      // 32768
static constexpr size_t OFF_IDXL  = 69632;                      // 524288
static constexpr size_t OFF_GX    = 593920;                     // 1572864
static constexpr size_t OFF_F1    = 2166784;                    // 16777216 f32
static constexpr size_t OFF_BIGA  = 18944000;                   // 67108864
static constexpr size_t OFF_BIGB  = 86052864;                   // 67108864
static constexpr size_t OFF_NET   = 153161728;                  // 2260992 f32 (8192x69)
static constexpr size_t OFF_WTH   = 155422720;                  // 1540096 bf16
static constexpr size_t OFF_WTL   = 156962816;                  // 1540096 bf16
// BIGA: L2OUT bf16 (0..33.5M, dead after L3); QF f32 (0..16.7M, from h2 on)
// BIGB: FEAT +0 (4M) | C1F +4M | C2F +8M | CLIPF +12M (8M) | H0F +20M (16M)
//       | H1F +36M (16M)

// Wt element offsets ([N][K] row-major bf16)
#define WT_GW1 0
#define WT_GW2 16384
#define WT_C1  32768
#define WT_C2  49152
#define WT_H0  65536
#define WT_H1  196608
#define WT_H2  458752
#define WT_C3  720896   // 384x128 (N padded, rows >=325 zero)

// sum-slot float offsets inside OFF_SUMS
#define SB0S 0
#define SB0Q 128
#define SB1S 256
#define SB1Q 384
#define SB2S 512
#define SB2Q 640
#define SC1S 768
#define SC1Q 896
#define SC2S 1024
#define SC2Q 1152
#define SH0S 1280
#define SH0Q 1792
#define SH1S 2304
#define SH1Q 2816

template <int CTRL>
__device__ __forceinline__ float fmax_dpp(float v) {
  int o = __builtin_amdgcn_update_dpp(0, __float_as_int(v), CTRL, 0xF, 0xF, true);
  return fmaxf(v, __int_as_float(o));
}

// fused: fps (0..15) | F1 gemm (16..527) | tnorm (528) | wprep (529..628)
__global__ __launch_bounds__(256, 1) void fused_pre(
    const float* __restrict__ xyz, int* __restrict__ inds,
    const float* __restrict__ features, const float* __restrict__ g_w0,
    float* __restrict__ F1, const float* __restrict__ text,
    float* __restrict__ tn, const float* __restrict__ g_w1,
    const float* __restrict__ g_w2, const float* __restrict__ conv1_w,
    const float* __restrict__ conv2_w, const float* __restrict__ conv3_w,
    const float* __restrict__ h_w0, const float* __restrict__ h_w1,
    const float* __restrict__ h_w2, unsigned short* __restrict__ wth,
    unsigned short* __restrict__ wtl) {
  __shared__ __align__(16) float smem[8208];
  const int tid = threadIdx.x;

  if (blockIdx.x < 16) {
    // ===== FPS: 4 waves, thread-major k = tid*8+j ==========================
    // Mailbox carries winner {key, x,y,z} (static-index tree carry, Rule #20).
    // NO global stores inside the loop: inds buffered in LDS so the per-iter
    // __syncthreads only drains lgkm (~30cy), not a vmcnt(0) HBM-store wait.
    #pragma clang fp contract(off)
    const int b = blockIdx.x;
    unsigned long long (*redk)[4] = (unsigned long long(*)[4])smem;  // 16 f
    float4 (*redc)[4] = (float4(*)[4])(smem + 16);                   // 32 f
    int* inds_s = (int*)(smem + 48);                                 // 512 i
    const float* base = xyz + (size_t)b * Kk * 3;
    if (tid == 0) inds_s[0] = 0;
    v2f PX[4], PY[4], PZ[4], DM[4];
    {
      const float* pb = base + tid * 24;
      float4 f0 = *(const float4*)(pb + 0);
      float4 f1 = *(const float4*)(pb + 4);
      float4 f2 = *(const float4*)(pb + 8);
      float4 f3 = *(const float4*)(pb + 12);
      float4 f4 = *(const float4*)(pb + 16);
      float4 f5 = *(const float4*)(pb + 20);
      PX[0] = (v2f){f0.x, f0.w}; PY[0] = (v2f){f0.y, f1.x}; PZ[0] = (v2f){f0.z, f1.y};
      PX[1] = (v2f){f1.z, f2.y}; PY[1] = (v2f){f1.w, f2.z}; PZ[1] = (v2f){f2.x, f2.w};
      PX[2] = (v2f){f3.x, f3.w}; PY[2] = (v2f){f3.y, f4.x}; PZ[2] = (v2f){f3.z, f4.y};
      PX[3] = (v2f){f4.z, f5.y}; PY[3] = (v2f){f4.w, f5.z}; PZ[3] = (v2f){f5.x, f5.w};
      #pragma unroll
      for (int p = 0; p < 4; p++) DM[p] = (v2f){1e10f, 1e10f};
    }
    // seed: point 0 (inds[0] = 0)
    float lx = base[0], ly = base[1], lz = base[2];
    const int lane = tid & 63, wid = tid >> 6;
    for (int it = 1; it < Pp; ++it) {
      v2f vlx = {lx, lx}, vly = {ly, ly}, vlz = {lz, lz};
      float pf[4], pcx[4], pcy[4], pcz[4];
      int pk_[4];
      #pragma unroll
      for (int p = 0; p < 4; p++) {
        v2f dx = PX[p] - vlx, dy = PY[p] - vly, dz = PZ[p] - vlz;
        v2f d = (dx * dx + dy * dy) + dz * dz;  // contract off: exact mul/add
        v2f m2 = __builtin_elementwise_min(DM[p], d);
        DM[p] = m2;
        bool t = m2.y > m2.x;                 // strict >: prefer lower index
        pf[p] = t ? m2.y : m2.x;
        pk_[p] = 2 * p + (t ? 1 : 0);
        pcx[p] = t ? PX[p].y : PX[p].x;       // compile-time p
        pcy[p] = t ? PY[p].y : PY[p].x;
        pcz[p] = t ? PZ[p].y : PZ[p].x;
      }
      // 2-level tree; carry key AND coords (all static indices)
      bool t01 = pf[1] > pf[0];
      float f01 = t01 ? pf[1] : pf[0];
      int k01 = t01 ? pk_[1] : pk_[0];
      float cx01 = t01 ? pcx[1] : pcx[0];
      float cy01 = t01 ? pcy[1] : pcy[0];
      float cz01 = t01 ? pcz[1] : pcz[0];
      bool t23 = pf[3] > pf[2];
      float f23 = t23 ? pf[3] : pf[2];
      int k23 = t23 ? pk_[3] : pk_[2];
      float cx23 = t23 ? pcx[3] : pcx[2];
      float cy23 = t23 ? pcy[3] : pcy[2];
      float cz23 = t23 ? pcz[3] : pcz[2];
      bool tt = f23 > f01;
      float bf = tt ? f23 : f01;
      int bk = tt ? k23 : k01;
      float wx = tt ? cx23 : cx01;
      float wy = tt ? cy23 : cy01;
      float wz = tt ? cz23 : cz01;
      float g = bf;
      g = fmax_dpp<0xB1>(g);   // xor 1
      g = fmax_dpp<0x4E>(g);   // xor 2
      g = fmax_dpp<0x141>(g);  // xor 7
      g = fmax_dpp<0x140>(g);  // xor 15
      g = fmax_dpp<0x142>(g);  // row_bcast15
      g = fmax_dpp<0x143>(g);  // row_bcast31 -> lane63 = wave max
      float gs = __uint_as_float(
          (unsigned)__builtin_amdgcn_readlane(__float_as_int(g), 63));
      unsigned long long msk = __ballot(bf == gs);
      int src = __builtin_ctzll(msk);  // lowest lane = lowest k (thread-major)
      if (lane == src) {
        int kk = (tid << 3) | bk;
        redk[it & 1][wid] = ((unsigned long long)__float_as_uint(gs) << 32) |
                            (unsigned)(~(unsigned)kk);
        redc[it & 1][wid] = make_float4(wx, wy, wz, 0.f);
      }
      __syncthreads();
      unsigned long long q0 = redk[it & 1][0], q1 = redk[it & 1][1];
      unsigned long long q2 = redk[it & 1][2], q3 = redk[it & 1][3];
      float4 c0 = redc[it & 1][0], c1 = redc[it & 1][1];
      float4 c2 = redc[it & 1][2], c3 = redc[it & 1][3];
      bool s01 = q0 > q1;
      unsigned long long m01 = s01 ? q0 : q1;
      float4 cc01 = s01 ? c0 : c1;
      bool s23 = q2 > q3;
      unsigned long long m23 = s23 ? q2 : q3;
      float4 cc23 = s23 ? c2 : c3;
      bool sw = m23 > m01;
      unsigned long long mm = sw ? m23 : m01;
      float4 cw = sw ? cc23 : cc01;
      lx = cw.x; ly = cw.y; lz = cw.z;
      if (tid == 0) inds_s[it] = (int)(~(unsigned)mm);  // LDS only
    }
    __syncthreads();
    for (int i = tid; i < Pp; i += 256) inds[b * Pp + i] = inds_s[i];
  } else if (blockIdx.x == 528) {
    int w = tid >> 6, lane = tid & 63;
    for (int r = w; r < 10; r += 4) {
      const float* rw = text + (size_t)r * 512;
      float v[8];
      float ss = 0.f;
      #pragma unroll
      for (int u = 0; u < 8; u++) { v[u] = rw[lane + 64 * u]; ss += v[u] * v[u]; }
      #pragma unroll
      for (int off = 32; off; off >>= 1) ss += __shfl_xor(ss, off, 64);
      float nrm = sqrtf(ss);
      #pragma unroll
      for (int u = 0; u < 8; u++)
        tn[(size_t)r * 512 + lane + 64 * u] = v[u] / nrm;
    }
  } else if (blockIdx.x >= 529) {
    // ===== weight transpose + RNE bf16 split (parallel, 100 blocks) =======
    int wb = blockIdx.x - 529;
    const float* W;
    int K, N, NS, nblk, pidx;
    unsigned short *dh, *dl;
    if (wb < 4)       { W = g_w1;    K = 128; N = 128; NS = 128; dh = wth + WT_GW1; dl = wtl + WT_GW1; nblk = 4;  pidx = wb; }
    else if (wb < 8)  { W = g_w2;    K = 128; N = 128; NS = 128; dh = wth + WT_GW2; dl = wtl + WT_GW2; nblk = 4;  pidx = wb - 4; }
    else if (wb < 12) { W = conv1_w; K = 128; N = 128; NS = 128; dh = wth + WT_C1;  dl = wtl + WT_C1;  nblk = 4;  pidx = wb - 8; }
    else if (wb < 16) { W = conv2_w; K = 128; N = 128; NS = 128; dh = wth + WT_C2;  dl = wtl + WT_C2;  nblk = 4;  pidx = wb - 12; }
    else if (wb < 32) { W = h_w0;    K = 256; N = 512; NS = 512; dh = wth + WT_H0;  dl = wtl + WT_H0;  nblk = 16; pidx = wb - 16; }
    else if (wb < 64) { W = h_w1;    K = 512; N = 512; NS = 512; dh = wth + WT_H1;  dl = wtl + WT_H1;  nblk = 32; pidx = wb - 32; }
    else if (wb < 96) { W = h_w2;    K = 512; N = 512; NS = 512; dh = wth + WT_H2;  dl = wtl + WT_H2;  nblk = 32; pidx = wb - 64; }
    else              { W = conv3_w; K = 128; N = 384; NS = 325; dh = wth + WT_C3;  dl = wtl + WT_C3;  nblk = 4;  pidx = wb - 96; }
    for (int idx = pidx * 256 + tid; idx < K * N; idx += nblk * 256) {
      int k = idx / N, n = idx - k * N;
      float w = (n < NS) ? W[k * NS + n] : 0.f;
      unsigned short hi = f2bf(w);
      unsigned short lo = f2bf(w - bf2f(hi));
      dh[n * K + k] = hi;
      dl[n * K + k] = lo;
    }
  } else {
    // ===== F1 = feats_kc @ g_w0[3:,:]  (32768 x 256 x 128) ================
    float (*a_t)[68] = (float(*)[68])smem;
    float (*b_t)[128] = (float(*)[128])(smem + 32 * 68);
    const float* W = g_w0 + 3 * 128;
    const int m0 = (blockIdx.x - 16) * 64;
    float acc[4][8];
    #pragma unroll
    for (int i = 0; i < 4; i++)
      #pragma unroll
      for (int j = 0; j < 8; j++) acc[i][j] = 0.f;
    const int ty = tid >> 4, tx = tid & 15;
    const int lr = tid & 63, wv = tid >> 6;
    const int bb = m0 >> 11, k0 = m0 & 2047;
    const float* fb = features + (size_t)bb * (Cc * Kk);
    for (int c0 = 0; c0 < 256; c0 += 32) {
      #pragma unroll
      for (int i = 0; i < 8; i++) {
        int c = c0 + wv + 4 * i;
        a_t[wv + 4 * i][lr] = fb[(size_t)c * Kk + k0 + lr];
      }
      #pragma unroll
      for (int p = 0; p < 4; p++) {
        int cc = p * 8 + (tid >> 5);
        int nl = (tid & 31) * 4;
        *(float4*)&b_t[cc][nl] = *(const float4*)&W[(size_t)(c0 + cc) * 128 + nl];
      }
      __syncthreads();
      #pragma unroll
      for (int kk = 0; kk < 32; kk++) {
        float4 av = *(const float4*)&a_t[kk][ty * 4];
        float4 b0 = *(const float4*)&b_t[kk][tx * 4];
        float4 b1 = *(const float4*)&b_t[kk][tx * 4 + 64];
        float ap[4] = {av.x, av.y, av.z, av.w};
        float bq0[4] = {b0.x, b0.y, b0.z, b0.w};
        float bq1[4] = {b1.x, b1.y, b1.z, b1.w};
        #pragma unroll
        for (int i = 0; i < 4; i++) {
          #pragma unroll
          for (int u = 0; u < 4; u++) {
            acc[i][u] = fmaf(ap[i], bq0[u], acc[i][u]);
            acc[i][4 + u] = fmaf(ap[i], bq1[u], acc[i][4 + u]);
          }
        }
      }
      __syncthreads();
    }
    #pragma unroll
    for (int i = 0; i < 4; i++) {
      size_t mrow = (size_t)(m0 + ty * 4 + i);
      #pragma unroll
      for (int gq = 0; gq < 2; gq++) {
        float4 v4 = make_float4(acc[i][gq * 4], acc[i][gq * 4 + 1],
                                acc[i][gq * 4 + 2], acc[i][gq * 4 + 3]);
        *(float4*)&F1[mrow * 128 + gq * 64 + tx * 4] = v4;
      }
    }
  }
}

// -------- neighbor selection + bn0 stats (xyz staged in LDS) --------
__global__ __launch_bounds__(256) void neigh_k(
    const float* __restrict__ xyz, const int* __restrict__ inds,
    const float* __restrict__ F1, const float* __restrict__ g_w0,
    int* __restrict__ idxl, float* __restrict__ gx, float* __restrict__ s0,
    float* __restrict__ q0) {
  __shared__ float rs[128], rq[128];
  __shared__ __align__(16) float4 pts[Kk];  // 32KB, all 4 waves same batch
  const int tid = threadIdx.x;
  if (tid < 128) { rs[tid] = 0.f; rq[tid] = 0.f; }
  int widx = blockIdx.x * 4 + (tid >> 6);
  int lane = tid & 63;
  int b = widx >> 9;
  const float* base = xyz + (size_t)b * Kk * 3;
  for (int i = tid; i < Kk; i += 256)
    pts[i] = make_float4(base[3 * i], base[3 * i + 1], base[3 * i + 2], 0.f);
  __syncthreads();
  int q = inds[widx];
  float4 Q = pts[q];
  float qx = Q.x, qy = Q.y, qz = Q.z;
  int cnt = 0;
  int myk = 0;
  for (int ch = 0; ch < 32 && cnt < Ss; ch++) {
    float4 P = pts[ch * 64 + lane];
    float dx = P.x - qx;
    float dy = P.y - qy;
    float dz = P.z - qz;
    float d2 = __fadd_rn(__fadd_rn(__fmul_rn(dx, dx), __fmul_rn(dy, dy)),
                         __fmul_rn(dz, dz));
    unsigned long long m = __ballot(d2 < 0.09f);
    while (m && cnt < Ss) {
      int t = __builtin_ctzll(m);
      if (lane == cnt) myk = ch * 64 + t;
      cnt++;
      m &= m - 1;
    }
  }
  int first = __shfl(myk, 0, 64);
  int kksel = 0;
  float g0r = 0.f, g1r = 0.f, g2r = 0.f;
  if (lane < Ss) {
    int kk = (lane < cnt) ? myk : first;
    kksel = kk;
    float4 P = pts[kk];
    g0r = (P.x - qx) / 0.3f;
    g1r = (P.y - qy) / 0.3f;
    g2r = (P.z - qz) / 0.3f;
    size_t o = (size_t)widx * Ss + lane;
    idxl[o] = kk;
    gx[o * 3 + 0] = g0r;
    gx[o * 3 + 1] = g1r;
    gx[o * 3 + 2] = g2r;
  }
  // ---- bn0 stats over the 16 gathered rows (cols: lane and lane+64) ----
  const float* f1b = F1 + (size_t)(b << 11) * 128;
  float wa0 = g_w0[lane], wa1 = g_w0[128 + lane], wa2 = g_w0[256 + lane];
  float wb0 = g_w0[64 + lane], wb1 = g_w0[192 + lane], wb2 = g_w0[320 + lane];
  float sa = 0.f, qa = 0.f, sb = 0.f, qb = 0.f;
  #pragma unroll
  for (int s = 0; s < Ss; s++) {
    int bidx = __shfl(kksel, s, 64);
    float gg0 = __shfl(g0r, s, 64);
    float gg1 = __shfl(g1r, s, 64);
    float gg2 = __shfl(g2r, s, 64);
    const float* fr = f1b + (size_t)bidx * 128;
    float va = fr[lane] + gg0 * wa0 + gg1 * wa1 + gg2 * wa2;
    float vb = fr[64 + lane] + gg0 * wb0 + gg1 * wb1 + gg2 * wb2;
    sa += va; qa += va * va;
    sb += vb; qb += vb * vb;
  }
  atomicAdd(&rs[lane], sa);
  atomicAdd(&rq[lane], qa);
  atomicAdd(&rs[64 + lane], sb);
  atomicAdd(&rq[64 + lane], qb);
  __syncthreads();
  if (tid < 128) {
    atomicAdd(&s0[tid], rs[tid]);
    atomicAdd(&q0[tid], rq[tid]);
  }
}

// ------- split-bf16 MFMA GEMM: out = act_in(A) @ (Wh+Wl)^T (+bias) ---------
// GATHER: A[row] = F1[gidx[row]] + gx(row).w_xyz  (inline gather, f32 src)
// ABF16 : A stored bf16. OBF16: store bf16.
// OMAX  : emit per-16-row-group max. WCLIP: split cols -> net / clipf.
template <int KD, bool INBN, bool HASBIAS, bool OSUM, bool OMAX, bool WCLIP,
          bool ABF16, bool GATHER, bool OBF16>
__global__ __launch_bounds__(256, 2) void gemm_mfma(
    const void* __restrict__ A, const unsigned short* __restrict__ Wh,
    const unsigned short* __restrict__ Wl, const float* __restrict__ bias,
    const float* __restrict__ isum, const float* __restrict__ isq,
    float inv_cnt, const float* __restrict__ gamma,
    const float* __restrict__ beta, void* __restrict__ outp, int N, int nout,
    float* __restrict__ clipf, float* __restrict__ osum,
    float* __restrict__ osq, const int* __restrict__ idxl,
    const float* __restrict__ gxv, const float* __restrict__ w0raw) {
  __shared__ float sc[INBN ? KD : 1];
  __shared__ float sh[INBN ? KD : 1];
  __shared__ float red_s[OSUM ? 128 : 1];
  __shared__ float red_q[OSUM ? 128 : 1];
  const int tid = threadIdx.x;
  if (INBN) {
    for (int c = tid; c < KD; c += 256) {
      float mean = isum[c] * inv_cnt;
      float var = isq[c] * inv_cnt - mean * mean;
      float is_ = rsqrtf(var + 1e-5f);
      float scl = gamma[c] * is_;
      sc[c] = scl;
      sh[c] = beta[c] - mean * scl;
    }
  }
  if (OSUM && tid < 128) { red_s[tid] = 0.f; red_q[tid] = 0.f; }
  __syncthreads();
  const int wave = tid >> 6, lane = tid & 63;
  const int wm = wave >> 1, wn = wave & 1;
  const int r = lane & 15, g = lane >> 4;
  const size_t m0 = (size_t)blockIdx.x * 128 + wm * 64;
  const int n0 = blockIdx.y * 128 + wn * 64;

  const float* Af = (const float*)A;
  const unsigned short* Ab = (const unsigned short*)A;

  size_t gi[4];
  float gx0[4], gx1[4], gx2[4];
  if (GATHER) {
    #pragma unroll
    for (int mf = 0; mf < 4; mf++) {
      int row = (int)m0 + mf * 16 + r;
      gi[mf] = ((size_t)((row >> 13) << 11) + idxl[row]) * 128;
      gx0[mf] = gxv[3 * (size_t)row];
      gx1[mf] = gxv[3 * (size_t)row + 1];
      gx2[mf] = gxv[3 * (size_t)row + 2];
    }
  }

  f32x4 acc[4][4] = {};
  for (int ks = 0; ks < KD / 32; ks++) {
    const int kb = ks * 32 + g * 8;
    bf16x8 bh[4], bl[4];
    #pragma unroll
    for (int nf = 0; nf < 4; nf++) {
      bh[nf] = *(const bf16x8*)&Wh[(size_t)(n0 + nf * 16 + r) * KD + kb];
      bl[nf] = *(const bf16x8*)&Wl[(size_t)(n0 + nf * 16 + r) * KD + kb];
    }
    float s8[8], h8[8];
    if (INBN) {
      #pragma unroll
      for (int j = 0; j < 8; j++) { s8[j] = sc[kb + j]; h8[j] = sh[kb + j]; }
    }
    float wxr[8], wyr[8], wzr[8];
    if (GATHER) {
      float4 a0 = *(const float4*)&w0raw[kb];
      float4 a1 = *(const float4*)&w0raw[kb + 4];
      float4 b0 = *(const float4*)&w0raw[128 + kb];
      float4 b1 = *(const float4*)&w0raw[128 + kb + 4];
      float4 c0 = *(const float4*)&w0raw[256 + kb];
      float4 c1 = *(const float4*)&w0raw[256 + kb + 4];
      wxr[0]=a0.x; wxr[1]=a0.y; wxr[2]=a0.z; wxr[3]=a0.w;
      wxr[4]=a1.x; wxr[5]=a1.y; wxr[6]=a1.z; wxr[7]=a1.w;
      wyr[0]=b0.x; wyr[1]=b0.y; wyr[2]=b0.z; wyr[3]=b0.w;
      wyr[4]=b1.x; wyr[5]=b1.y; wyr[6]=b1.z; wyr[7]=b1.w;
      wzr[0]=c0.x; wzr[1]=c0.y; wzr[2]=c0.z; wzr[3]=c0.w;
      wzr[4]=c1.x; wzr[5]=c1.y; wzr[6]=c1.z; wzr[7]=c1.w;
    }
    #pragma unroll
    for (int mf = 0; mf < 4; mf++) {
      float xv[8];
      if (GATHER) {
        const float* fp = Af + gi[mf] + kb;
        float4 x0 = *(const float4*)fp;
        float4 x1 = *(const float4*)(fp + 4);
        xv[0]=x0.x; xv[1]=x0.y; xv[2]=x0.z; xv[3]=x0.w;
        xv[4]=x1.x; xv[5]=x1.y; xv[6]=x1.z; xv[7]=x1.w;
        #pragma unroll
        for (int j = 0; j < 8; j++)
          xv[j] += gx0[mf] * wxr[j] + gx1[mf] * wyr[j] + gx2[mf] * wzr[j];
      } else if (ABF16) {
        bf16x8 rawv = *(const bf16x8*)&Ab[(m0 + mf * 16 + r) * KD + kb];
        #pragma unroll
        for (int j = 0; j < 8; j++) xv[j] = bf2f((unsigned short)rawv[j]);
      } else {
        const float* ap = Af + (m0 + mf * 16 + r) * KD + kb;
        float4 x0 = *(const float4*)ap;
        float4 x1 = *(const float4*)(ap + 4);
        xv[0]=x0.x; xv[1]=x0.y; xv[2]=x0.z; xv[3]=x0.w;
        xv[4]=x1.x; xv[5]=x1.y; xv[6]=x1.z; xv[7]=x1.w;
      }
      bf16x8 ah, al;
      #pragma unroll
      for (int j = 0; j < 8; j++) {
        float x = xv[j];
        if (INBN) x = fmaxf(fmaf(x, s8[j], h8[j]), 0.f);
        short hh, ll;
        split2(x, hh, ll);
        ah[j] = hh;
        al[j] = ll;
      }
      #pragma unroll
      for (int nf = 0; nf < 4; nf++) {
        acc[mf][nf] = __builtin_amdgcn_mfma_f32_16x16x32_bf16(
            ah, bh[nf], acc[mf][nf], 0, 0, 0);
        acc[mf][nf] = __builtin_amdgcn_mfma_f32_16x16x32_bf16(
            al, bh[nf], acc[mf][nf], 0, 0, 0);
        acc[mf][nf] = __builtin_amdgcn_mfma_f32_16x16x32_bf16(
            ah, bl[nf], acc[mf][nf], 0, 0, 0);
      }
    }
  }
  float bv[4];
  if (HASBIAS) {
    #pragma unroll
    for (int nf = 0; nf < 4; nf++) {
      int col = n0 + nf * 16 + r;
      bv[nf] = (!WCLIP || col < nout) ? bias[col] : 0.f;
    }
  }
  float ps[4] = {0.f, 0.f, 0.f, 0.f}, pq[4] = {0.f, 0.f, 0.f, 0.f};
  #pragma unroll
  for (int mf = 0; mf < 4; mf++) {
    float mx[4];
    #pragma unroll
    for (int nf = 0; nf < 4; nf++) {
      float vmax = -1e30f;
      #pragma unroll
      for (int j = 0; j < 4; j++) {
        float v = acc[mf][nf][j];
        if (HASBIAS) v += bv[nf];
        size_t row = m0 + mf * 16 + g * 4 + j;
        int col = n0 + nf * 16 + r;
        if (OSUM) { ps[nf] += v; pq[nf] += v * v; }
        if (OMAX) {
          vmax = fmaxf(vmax, v);
        } else if (WCLIP) {
          if (col < 69) ((float*)outp)[row * 69 + col] = v;
          else if (col < nout) clipf[row * 256 + (col - 69)] = v;
        } else if (OBF16) {
          ((unsigned short*)outp)[row * N + col] = f2bf(v);
        } else {
          ((float*)outp)[row * N + col] = v;
        }
      }
      mx[nf] = vmax;
    }
    if (OMAX) {
      #pragma unroll
      for (int nf = 0; nf < 4; nf++) {
        float m = mx[nf];
        m = fmaxf(m, __shfl_xor(m, 16, 64));
        m = fmaxf(m, __shfl_xor(m, 32, 64));
        if (g == 0) {
          size_t bq = (m0 >> 4) + mf;
          ((float*)outp)[bq * 128 + n0 + nf * 16 + r] = m;
        }
      }
    }
  }
  if (OSUM) {
    #pragma unroll
    for (int nf = 0; nf < 4; nf++) {
      #pragma unroll
      for (int off = 16; off < 64; off <<= 1) {
        ps[nf] += __shfl_xor(ps[nf], off, 64);
        pq[nf] += __shfl_xor(pq[nf], off, 64);
      }
    }
    if (lane < 16) {
      #pragma unroll
      for (int nf = 0; nf < 4; nf++) {
        int lcol = wn * 64 + nf * 16 + r;
        atomicAdd(&red_s[lcol], ps[nf]);
        atomicAdd(&red_q[lcol], pq[nf]);
      }
    }
    __syncthreads();
    if (tid < 128) {
      atomicAdd(&osum[blockIdx.y * 128 + tid], red_s[tid]);
      atomicAdd(&osq[blockIdx.y * 128 + tid], red_q[tid]);
    }
  }
}

// ---------------- final: q-norm, logits, coalesced transpose-assemble -------
__global__ __launch_bounds__(512) void final2(const float* __restrict__ net,
                                              const float* __restrict__ qbuf,
                                              const float* __restrict__ tn,
                                              float* __restrict__ out) {
  __shared__ float tile[79][65];
  const int blk = blockIdx.x;
  const int tid = threadIdx.x;
  const int r = tid >> 3, oct = tid & 7;
  const int row = blk * 64 + r;
  const int b = (blk * 64) >> 9, p0 = (blk * 64) & 511;

  const float* qr = qbuf + (size_t)row * 512 + oct * 64;
  float4 q4[16];
  #pragma unroll
  for (int i = 0; i < 16; i++) q4[i] = *(const float4*)(qr + 4 * i);
  float ss = 0.f;
  float dot[10];
  #pragma unroll
  for (int t = 0; t < 10; t++) dot[t] = 0.f;
  #pragma unroll
  for (int i = 0; i < 16; i++) {
    float4 a = q4[i];
    ss += a.x * a.x + a.y * a.y + a.z * a.z + a.w * a.w;
    #pragma unroll
    for (int t = 0; t < 10; t++) {
      float4 b4 = *(const float4*)(tn + (size_t)t * 512 + oct * 64 + i * 4);
      dot[t] += a.x * b4.x + a.y * b4.y + a.z * b4.z + a.w * b4.w;
    }
  }
  #pragma unroll
  for (int off = 1; off < 8; off <<= 1) {
    ss += __shfl_xor(ss, off, 8);
    #pragma unroll
    for (int t = 0; t < 10; t++) dot[t] += __shfl_xor(dot[t], off, 8);
  }
  if (oct == 0) {
    float inv = rsqrtf(ss) * (1.f / 0.07f);
    #pragma unroll
    for (int t = 0; t < 10; t++) tile[69 + t][r] = dot[t] * inv;
  }
  for (int idx = tid; idx < 64 * 69; idx += 512) {
    int r2 = idx / 69, ch = idx - 69 * r2;
    tile[ch][r2] = net[(size_t)(blk * 64 + r2) * 69 + ch];
  }
  __syncthreads();
  for (int idx = tid; idx < 79 * 64; idx += 512) {
    int ch = idx >> 6, rr = idx & 63;
    out[((size_t)b * 79 + ch) * 512 + p0 + rr] = tile[ch][rr];
  }
}

extern "C" void kernel_launch(void* const* d_in, const int* in_sizes, int n_in,
                              void* d_out, int out_size, void* d_ws,
                              size_t ws_size, hipStream_t stream) {
  const float* xyz = (const float*)d_in[0];
  const float* features = (const float*)d_in[1];
  const float* text = (const float*)d_in[2];
  const float* g_w0 = (const float*)d_in[3];
  const float* g_w1 = (const float*)d_in[4];
  const float* g_w2 = (const float*)d_in[5];
  const float* g_gam0 = (const float*)d_in[6];
  const float* g_bet0 = (const float*)d_in[7];
  const float* g_gam1 = (const float*)d_in[8];
  const float* g_bet1 = (const float*)d_in[9];
  const float* g_gam2 = (const float*)d_in[10];
  const float* g_bet2 = (const float*)d_in[11];
  const float* conv1_w = (const float*)d_in[12];
  const float* conv1_b = (const float*)d_in[13];
  const float* bn1_g = (const float*)d_in[14];
  const float* bn1_b = (const float*)d_in[15];
  const float* conv2_w = (const float*)d_in[16];
  const float* conv2_b = (const float*)d_in[17];
  const float* bn2_g = (const float*)d_in[18];
  const float* bn2_b = (const float*)d_in[19];
  const float* conv3_w = (const float*)d_in[20];
  const float* conv3_b = (const float*)d_in[21];
  const float* h_w0 = (const float*)d_in[22];
  const float* h_b0 = (const float*)d_in[23];
  const float* h_g0 = (const float*)d_in[24];
  const float* h_be0 = (const float*)d_in[25];
  const float* h_w1 = (const float*)d_in[26];
  const float* h_b1 = (const float*)d_in[27];
  const float* h_g1 = (const float*)d_in[28];
  const float* h_be1 = (const float*)d_in[29];
  const float* h_w2 = (const float*)d_in[30];
  const float* h_b2 = (const float*)d_in[31];
  float* out = (float*)d_out;
  char* ws = (char*)d_ws;

  float* tn = (float*)(ws + OFF_TNORM);
  float* sums = (float*)(ws + OFF_SUMS);
  int* inds = (int*)(ws + OFF_INDS);
  int* idxl = (int*)(ws + OFF_IDXL);
  float* gx = (float*)(ws + OFF_GX);
  float* F1 = (float*)(ws + OFF_F1);
  unsigned short* L2OUT = (unsigned short*)(ws + OFF_BIGA);
  float* QF = (float*)(ws + OFF_BIGA);
  float* FEAT = (float*)(ws + OFF_BIGB);
  float* C1F = (float*)(ws + OFF_BIGB + 4194304);
  float* C2F = (float*)(ws + OFF_BIGB + 8388608);
  float* CLIPF = (float*)(ws + OFF_BIGB + 12582912);
  float* H0F = (float*)(ws + OFF_BIGB + 20971520);
  float* H1F = (float*)(ws + OFF_BIGB + 37748736);
  float* net = (float*)(ws + OFF_NET);
  unsigned short* WTH = (unsigned short*)(ws + OFF_WTH);
  unsigned short* WTL = (unsigned short*)(ws + OFF_WTL);

  hipMemsetAsync(sums, 0, 16384, stream);
  fused_pre<<<629, 256, 0, stream>>>(xyz, inds, features, g_w0, F1, text, tn,
                                     g_w1, g_w2, conv1_w, conv2_w, conv3_w,
                                     h_w0, h_w1, h_w2, WTH, WTL);
  // neighbor selection + bn0 stats
  neigh_k<<<2048, 256, 0, stream>>>(xyz, inds, F1, g_w0, idxl, gx,
                                    sums + SB0S, sums + SB0Q);
  // L2 = relu(bn0(gather(F1)+gx.w)) @ g_w1  (inline gather, bf16 out)
  gemm_mfma<128, true, false, true, false, false, false, true, true>
      <<<dim3(1024, 1), 256, 0, stream>>>(
          F1, WTH + WT_GW1, WTL + WT_GW1, nullptr, sums + SB0S, sums + SB0Q,
          1.f / 131072.f, g_gam0, g_bet0, L2OUT, 128, 128, nullptr,
          sums + SB1S, sums + SB1Q, idxl, gx, g_w0);
  // L3 = relu(bn1(L2)) @ g_w2, fused raw max over S=16 -> FEAT (+bn2 stats)
  gemm_mfma<128, true, false, true, true, false, true, false, false>
      <<<dim3(1024, 1), 256, 0, stream>>>(
          L2OUT, WTH + WT_GW2, WTL + WT_GW2, nullptr, sums + SB1S,
          sums + SB1Q, 1.f / 131072.f, g_gam1, g_bet1, FEAT, 128, 128,
          nullptr, sums + SB2S, sums + SB2Q, nullptr, nullptr, nullptr);
  // c1 = relu(bn2(feat)) @ conv1_w + b
  gemm_mfma<128, true, true, true, false, false, false, false, false>
      <<<dim3(64, 1), 256, 0, stream>>>(
          FEAT, WTH + WT_C1, WTL + WT_C1, conv1_b, sums + SB2S, sums + SB2Q,
          1.f / 131072.f, g_gam2, g_bet2, C1F, 128, 128, nullptr, sums + SC1S,
          sums + SC1Q, nullptr, nullptr, nullptr);
  // c2 = relu(bn(c1)) @ conv2_w + b
  gemm_mfma<128, true, true, true, false, false, false, false, false>
      <<<dim3(64, 1), 256, 0, stream>>>(
          C1F, WTH + WT_C2, WTL + WT_C2, conv2_b, sums + SC1S, sums + SC1Q,
          1.f / 8192.f, bn1_g, bn1_b, C2F, 128, 128, nullptr, sums + SC2S,
          sums + SC2Q, nullptr, nullptr, nullptr);
  // net/clip = relu(bn(c2)) @ conv3_w + b  (N padded 384, nout=325)
  gemm_mfma<128, true, true, false, false, true, false, false, false>
      <<<dim3(64, 3), 256, 0, stream>>>(
          C2F, WTH + WT_C3, WTL + WT_C3, conv3_b, sums + SC2S, sums + SC2Q,
          1.f / 8192.f, bn2_g, bn2_b, net, 384, 325, CLIPF, nullptr, nullptr,
          nullptr, nullptr, nullptr);
  // h0 = clip_in @ h_w0 + b
  gemm_mfma<256, false, true, true, false, false, false, false, false>
      <<<dim3(64, 4), 256, 0, stream>>>(
          CLIPF, WTH + WT_H0, WTL + WT_H0, h_b0, nullptr, nullptr, 0.f,
          nullptr, nullptr, H0F, 512, 512, nullptr, sums + SH0S, sums + SH0Q,
          nullptr, nullptr, nullptr);
  // h1 = relu(bn(h0)) @ h_w1 + b
  gemm_mfma<512, true, true, true, false, false, false, false, false>
      <<<dim3(64, 4), 256, 0, stream>>>(
          H0F, WTH + WT_H1, WTL + WT_H1, h_b1, sums + SH0S, sums + SH0Q,
          1.f / 8192.f, h_g0, h_be0, H1F, 512, 512, nullptr, sums + SH1S,
          sums + SH1Q, nullptr, nullptr, nullptr);
  // q = relu(bn(h1)) @ h_w2 + b
  gemm_mfma<512, true, true, false, false, false, false, false, false>
      <<<dim3(64, 4), 256, 0, stream>>>(
          H1F, WTH + WT_H2, WTL + WT_H2, h_b2, sums + SH1S, sums + SH1Q,
          1.f / 8192.f, h_g1, h_be1, QF, 512, 512, nullptr, nullptr, nullptr,
          nullptr, nullptr, nullptr);
  final2<<<128, 512, 0, stream>>>(net, QF, tn, out);
}